// Round 1
// baseline (916.602 us; speedup 1.0000x reference)
//
#include <hip/hip_runtime.h>

// SGC: K=2 hops of D^-1/2 A D^-1/2 (with self loops) then x@W+b then log_softmax.
// N=100000, D=64, C=40, E=1600000.

#define D_FEAT 64

__global__ void init_deg_kernel(float* __restrict__ deg, int n) {
    int i = blockIdx.x * blockDim.x + threadIdx.x;
    if (i < n) deg[i] = 1.0f;  // self-loop contributes 1 to out-degree
}

__global__ void accum_deg_kernel(const int* __restrict__ rows, float* __restrict__ deg, int e) {
    int i = blockIdx.x * blockDim.x + threadIdx.x;
    if (i < e) atomicAdd(&deg[rows[i]], 1.0f);
}

__global__ void rsqrt_deg_kernel(float* __restrict__ deg, int n) {
    int i = blockIdx.x * blockDim.x + threadIdx.x;
    if (i < n) deg[i] = rsqrtf(deg[i]);  // deg >= 1 always (self loop)
}

// xout[i,:] = dis[i]^2 * xin[i,:]   (the self-loop edge, also serves as init)
__global__ void spmm_self_kernel(const float* __restrict__ xin, float* __restrict__ xout,
                                 const float* __restrict__ dis, int n) {
    int i = blockIdx.x * blockDim.x + threadIdx.x;  // over n * (D/4) float4s
    int total = n * (D_FEAT / 4);
    if (i < total) {
        int node = i / (D_FEAT / 4);
        float s = dis[node];
        s = s * s;
        float4 v = ((const float4*)xin)[i];
        v.x *= s; v.y *= s; v.z *= s; v.w *= s;
        ((float4*)xout)[i] = v;
    }
}

// One wave-lane per (edge, feature): lanes 0..63 of a wave share one edge.
// xout[r, d] += dis[r]*dis[c] * xin[c, d]
__global__ void spmm_edge_kernel(const float* __restrict__ xin, float* __restrict__ xout,
                                 const int* __restrict__ rows, const int* __restrict__ cols,
                                 const float* __restrict__ dis, int e) {
    long long t = (long long)blockIdx.x * blockDim.x + threadIdx.x;
    int eidx = (int)(t >> 6);
    int d = (int)(t & 63);
    if (eidx < e) {
        int r = rows[eidx];
        int c = cols[eidx];
        float nrm = dis[r] * dis[c];
        atomicAdd(&xout[(long long)r * D_FEAT + d], nrm * xin[(long long)c * D_FEAT + d]);
    }
}

// Per-node: logits = x_row @ W + b, then log_softmax. W (64x40) staged in LDS.
__global__ __launch_bounds__(256) void logits_kernel(const float* __restrict__ x,
                                                     const float* __restrict__ W,
                                                     const float* __restrict__ b,
                                                     float* __restrict__ out,
                                                     int n, int ncls) {
    extern __shared__ float smem[];          // D*ncls + ncls floats
    float* Wl = smem;
    float* bl = smem + D_FEAT * ncls;
    for (int i = threadIdx.x; i < D_FEAT * ncls; i += blockDim.x) Wl[i] = W[i];
    for (int i = threadIdx.x; i < ncls; i += blockDim.x) bl[i] = b[i];
    __syncthreads();

    int node = blockIdx.x * blockDim.x + threadIdx.x;
    if (node >= n) return;

    float xr[D_FEAT];
    const float4* xp = (const float4*)(x + (long long)node * D_FEAT);
#pragma unroll
    for (int i = 0; i < D_FEAT / 4; i++) {
        float4 v = xp[i];
        xr[4 * i + 0] = v.x; xr[4 * i + 1] = v.y;
        xr[4 * i + 2] = v.z; xr[4 * i + 3] = v.w;
    }

    // ncls is 40 at runtime; use fixed 40 for full unroll (guarded)
    const int C = 40;
    float acc[C];
#pragma unroll
    for (int c = 0; c < C; c++) acc[c] = bl[c];
    for (int d = 0; d < D_FEAT; d++) {
        float xv = xr[d];
#pragma unroll
        for (int c = 0; c < C; c++) acc[c] += xv * Wl[d * C + c];  // broadcast read, no bank conflict
    }

    float m = acc[0];
#pragma unroll
    for (int c = 1; c < C; c++) m = fmaxf(m, acc[c]);
    float s = 0.0f;
#pragma unroll
    for (int c = 0; c < C; c++) s += __expf(acc[c] - m);
    float lse = m + __logf(s);

    float* op = out + (long long)node * C;
#pragma unroll
    for (int c = 0; c < C; c++) op[c] = acc[c] - lse;
}

extern "C" void kernel_launch(void* const* d_in, const int* in_sizes, int n_in,
                              void* d_out, int out_size, void* d_ws, size_t ws_size,
                              hipStream_t stream) {
    const float* x  = (const float*)d_in[0];
    const int*   ei = (const int*)d_in[1];   // [2, E] flat: rows then cols (int32 per harness)
    const float* W  = (const float*)d_in[2]; // [64, C]
    const float* b  = (const float*)d_in[3]; // [C]
    float* out = (float*)d_out;

    const int n = in_sizes[0] / D_FEAT;      // 100000
    const int e = in_sizes[1] / 2;           // 1600000
    const int c = in_sizes[2] / D_FEAT;      // 40

    const int* rows = ei;
    const int* cols = ei + e;

    // workspace layout: dis[n] (aligned), x1[n*64], x2[n*64]  (~51.6 MB)
    float* dis = (float*)d_ws;
    size_t dis_elems = ((size_t)n + 255) & ~(size_t)255;
    float* x1 = dis + dis_elems;
    float* x2 = x1 + (size_t)n * D_FEAT;

    const int BS = 256;

    // 1) degree (incl self loop)
    init_deg_kernel<<<(n + BS - 1) / BS, BS, 0, stream>>>(dis, n);
    accum_deg_kernel<<<(e + BS - 1) / BS, BS, 0, stream>>>(rows, dis, e);
    rsqrt_deg_kernel<<<(n + BS - 1) / BS, BS, 0, stream>>>(dis, n);

    // 2) hop 1: x -> x1
    {
        int tot = n * (D_FEAT / 4);
        spmm_self_kernel<<<(tot + BS - 1) / BS, BS, 0, stream>>>(x, x1, dis, n);
        long long work = (long long)e * D_FEAT;
        int blocks = (int)((work + BS - 1) / BS);
        spmm_edge_kernel<<<blocks, BS, 0, stream>>>(x, x1, rows, cols, dis, e);
    }
    // 3) hop 2: x1 -> x2
    {
        int tot = n * (D_FEAT / 4);
        spmm_self_kernel<<<(tot + BS - 1) / BS, BS, 0, stream>>>(x1, x2, dis, n);
        long long work = (long long)e * D_FEAT;
        int blocks = (int)((work + BS - 1) / BS);
        spmm_edge_kernel<<<blocks, BS, 0, stream>>>(x1, x2, rows, cols, dis, e);
    }

    // 4) logits + log_softmax
    {
        size_t smem = (size_t)(D_FEAT * c + c) * sizeof(float);
        logits_kernel<<<(n + BS - 1) / BS, BS, smem, stream>>>(x2, W, b, out, n, c);
    }
}

// Round 2
// 599.523 us; speedup vs baseline: 1.5289x; 1.5289x over previous
//
#include <hip/hip_runtime.h>
#include <math.h>

// SGC: K=2 hops of D^-1/2 (A+I) D^-1/2, then x@W+b, then log_softmax.
// N=100000, D=64, C=40, E=1600000.
// Strategy: build CSR once (counts -> scan -> scatter), then gather-SpMM
// with one 64-lane wave per row (lane = feature). Hop 2 is fused with the
// 64x40 GEMV + log_softmax epilogue (no x2 buffer, no atomics anywhere hot).

#define D_FEAT 64
#define NCLS 40

__global__ void zero_ints_kernel(int* __restrict__ a, int* __restrict__ b, int n) {
    int i = blockIdx.x * blockDim.x + threadIdx.x;
    if (i < n) { a[i] = 0; b[i] = 0; }
}

__global__ void count_rows_kernel(const int* __restrict__ rows, int* __restrict__ counts, int e) {
    int i = blockIdx.x * blockDim.x + threadIdx.x;
    if (i < e) atomicAdd(&counts[rows[i]], 1);
}

// Per-256-block exclusive scan of counts; also emits dis = rsqrt(1+deg).
__global__ void scan_blocks_kernel(const int* __restrict__ counts, int* __restrict__ row_start,
                                   int* __restrict__ partial, float* __restrict__ dis, int n) {
    __shared__ int sm[256];
    int i = blockIdx.x * 256 + threadIdx.x;
    int v = (i < n) ? counts[i] : 0;
    if (i < n) dis[i] = rsqrtf(1.0f + (float)v);  // self loop -> deg >= 1
    sm[threadIdx.x] = v;
    __syncthreads();
    for (int off = 1; off < 256; off <<= 1) {
        int t = (threadIdx.x >= off) ? sm[threadIdx.x - off] : 0;
        __syncthreads();
        sm[threadIdx.x] += t;
        __syncthreads();
    }
    if (i < n) row_start[i] = sm[threadIdx.x] - v;  // exclusive
    if (threadIdx.x == 255) partial[blockIdx.x] = sm[255];
}

// Single-block exclusive scan of the per-block partial sums (P <= 1024).
__global__ void scan_partials_kernel(int* __restrict__ partial, int P) {
    __shared__ int sm[1024];
    int v = (threadIdx.x < P) ? partial[threadIdx.x] : 0;
    sm[threadIdx.x] = v;
    __syncthreads();
    for (int off = 1; off < 1024; off <<= 1) {
        int t = (threadIdx.x >= off) ? sm[threadIdx.x - off] : 0;
        __syncthreads();
        sm[threadIdx.x] += t;
        __syncthreads();
    }
    if (threadIdx.x < P) partial[threadIdx.x] = sm[threadIdx.x] - v;  // exclusive
}

__global__ void add_offsets_kernel(int* __restrict__ row_start, const int* __restrict__ partial,
                                   int n, int e) {
    int i = blockIdx.x * blockDim.x + threadIdx.x;
    if (i < n) row_start[i] += partial[i >> 8];
    if (i == 0) row_start[n] = e;
}

__global__ void fill_csr_kernel(const int* __restrict__ rows, const int* __restrict__ cols,
                                const int* __restrict__ row_start, int* __restrict__ cursor,
                                int* __restrict__ csr_col, int e) {
    int i = blockIdx.x * blockDim.x + threadIdx.x;
    if (i < e) {
        int r = rows[i];
        int pos = row_start[r] + atomicAdd(&cursor[r], 1);
        csr_col[pos] = cols[i];
    }
}

// Hop 1: one wave per row, lane = feature.
// out[r,d] = dis[r] * ( dis[r]*x[r,d] + sum_c dis[c]*x[c,d] )
__global__ __launch_bounds__(256) void spmm_csr_kernel(const float* __restrict__ xin,
                                                       float* __restrict__ xout,
                                                       const int* __restrict__ row_start,
                                                       const int* __restrict__ csr_col,
                                                       const float* __restrict__ dis, int n) {
    int wave = (blockIdx.x * blockDim.x + threadIdx.x) >> 6;
    int lane = threadIdx.x & 63;
    if (wave >= n) return;
    int r = wave;
    float dr = dis[r];
    float acc = dr * xin[r * D_FEAT + lane];
    int s = row_start[r], t = row_start[r + 1];
    if (s < t) {
        int c = csr_col[s];
        for (int j = s; j < t; j++) {
            int cn = (j + 1 < t) ? csr_col[j + 1] : 0;  // prefetch next col
            acc += dis[c] * xin[c * D_FEAT + lane];
            c = cn;
        }
    }
    xout[r * D_FEAT + lane] = dr * acc;
}

// Hop 2 fused with logits + log_softmax. One wave per row; acc stays in the
// wave; GEMV via __shfl broadcast of each feature against LDS-staged W.
__global__ __launch_bounds__(256) void spmm_logits_kernel(const float* __restrict__ xin,
                                                          const int* __restrict__ row_start,
                                                          const int* __restrict__ csr_col,
                                                          const float* __restrict__ dis,
                                                          const float* __restrict__ W,
                                                          const float* __restrict__ b,
                                                          float* __restrict__ out, int n) {
    __shared__ float Wl[D_FEAT * NCLS];
    __shared__ float bl[NCLS];
    for (int i = threadIdx.x; i < D_FEAT * NCLS; i += blockDim.x) Wl[i] = W[i];
    for (int i = threadIdx.x; i < NCLS; i += blockDim.x) bl[i] = b[i];
    __syncthreads();

    int wave = (blockIdx.x * blockDim.x + threadIdx.x) >> 6;
    int lane = threadIdx.x & 63;
    if (wave >= n) return;
    int r = wave;
    float dr = dis[r];
    float acc = dr * xin[r * D_FEAT + lane];
    int s = row_start[r], t = row_start[r + 1];
    if (s < t) {
        int c = csr_col[s];
        for (int j = s; j < t; j++) {
            int cn = (j + 1 < t) ? csr_col[j + 1] : 0;
            acc += dis[c] * xin[c * D_FEAT + lane];
            c = cn;
        }
    }
    acc *= dr;  // final hop-2 feature d=lane of row r

    // GEMV: y[c] = b[c] + sum_d acc_d * W[d,c], c = lane (lanes 40..63 idle-ish)
    int wl = (lane < NCLS) ? lane : 0;  // keep LDS index in range for inactive lanes
    float yv = bl[wl];
#pragma unroll
    for (int d = 0; d < D_FEAT; d++) {
        float xv = __shfl(acc, d, 64);
        yv += xv * Wl[d * NCLS + wl];
    }
    float y = (lane < NCLS) ? yv : -INFINITY;

    // wave-wide log_softmax over the 40 valid lanes
    float m = y;
#pragma unroll
    for (int o = 32; o > 0; o >>= 1) m = fmaxf(m, __shfl_xor(m, o, 64));
    float sfull = __expf(y - m);  // lanes >= 40: exp(-inf) = 0
#pragma unroll
    for (int o = 32; o > 0; o >>= 1) sfull += __shfl_xor(sfull, o, 64);
    float lse = m + __logf(sfull);

    if (lane < NCLS) out[r * NCLS + lane] = y - lse;
}

extern "C" void kernel_launch(void* const* d_in, const int* in_sizes, int n_in,
                              void* d_out, int out_size, void* d_ws, size_t ws_size,
                              hipStream_t stream) {
    const float* x  = (const float*)d_in[0];
    const int*   ei = (const int*)d_in[1];   // [2, E] flat: rows then cols (int32)
    const float* W  = (const float*)d_in[2]; // [64, 40]
    const float* b  = (const float*)d_in[3]; // [40]
    float* out = (float*)d_out;

    const int n = in_sizes[0] / D_FEAT;      // 100000
    const int e = in_sizes[1] / 2;           // 1600000

    const int* rows = ei;
    const int* cols = ei + e;

    // workspace layout (ints/floats, all 256-element aligned):
    //   counts[n] | cursor[n] | row_start[n+1] | partial[P] | dis[n] | csr_col[e] | x1[n*64]
    size_t na = ((size_t)n + 256) & ~(size_t)255;
    int*   counts    = (int*)d_ws;
    int*   cursor    = counts + na;
    int*   row_start = cursor + na;
    int    P         = (n + 255) / 256;
    int*   partial   = row_start + na;
    float* dis       = (float*)(partial + (((size_t)P + 255) & ~(size_t)255));
    int*   csr_col   = (int*)(dis + na);
    float* x1        = (float*)(csr_col + (((size_t)e + 255) & ~(size_t)255));

    const int BS = 256;

    zero_ints_kernel<<<(n + BS - 1) / BS, BS, 0, stream>>>(counts, cursor, n);
    count_rows_kernel<<<(e + BS - 1) / BS, BS, 0, stream>>>(rows, counts, e);
    scan_blocks_kernel<<<P, BS, 0, stream>>>(counts, row_start, partial, dis, n);
    scan_partials_kernel<<<1, 1024, 0, stream>>>(partial, P);
    add_offsets_kernel<<<(n + BS - 1) / BS, BS, 0, stream>>>(row_start, partial, n, e);
    fill_csr_kernel<<<(e + BS - 1) / BS, BS, 0, stream>>>(rows, cols, row_start, cursor, csr_col, e);

    int spmm_blocks = (n + 3) / 4;  // 4 waves (rows) per 256-thread block
    spmm_csr_kernel<<<spmm_blocks, BS, 0, stream>>>(x, x1, row_start, csr_col, dis, n);
    spmm_logits_kernel<<<spmm_blocks, BS, 0, stream>>>(x1, row_start, csr_col, dis, W, b, out, n);
}

// Round 3
// 444.332 us; speedup vs baseline: 2.0629x; 1.3493x over previous
//
#include <hip/hip_runtime.h>
#include <math.h>

// SGC: K=2 hops of D^-1/2 (A+I) D^-1/2, then x@W+b, then log_softmax.
// N=100000, D=64, C=40, E=1600000.
//
// R3 strategy: CSR gather-SpMM, one 64-lane wave per row (lane = feature).
// - Intermediate arrays carry dis-scaled features xs = dis ⊙ h, so the inner
//   loop is pure "acc += xs[c*64+lane]" (no dis[c] gather, no FMA chain).
// - CSR rows padded to a multiple of 8 with a dummy node (xs[dummy]=0) so the
//   neighbor loop is branch-free and unrolled x8 with 8 independent
//   accumulators -> 8 gathers in flight per wave (latency-bound fix).
// - Hop 2 fused with 64x40 GEMV (shfl broadcast vs LDS-staged W) + log_softmax.

#define D_FEAT 64
#define NCLS 40
#define RPAD 8   // row padding multiple (== unroll factor)

__global__ void zero_ints_kernel(int* __restrict__ a, int* __restrict__ b, int n) {
    int i = blockIdx.x * blockDim.x + threadIdx.x;
    if (i < n) { a[i] = 0; b[i] = 0; }
}

__global__ void count_rows_kernel(const int* __restrict__ rows, int* __restrict__ counts, int e) {
    int i = blockIdx.x * blockDim.x + threadIdx.x;
    if (i < e) atomicAdd(&counts[rows[i]], 1);
}

// Per-256-block exclusive scan of PADDED counts; also emits dis = rsqrt(1+deg).
__global__ void scan_blocks_kernel(const int* __restrict__ counts, int* __restrict__ row_start,
                                   int* __restrict__ partial, float* __restrict__ dis, int n) {
    __shared__ int sm[256];
    int i = blockIdx.x * 256 + threadIdx.x;
    int c = (i < n) ? counts[i] : 0;
    int v = (c + (RPAD - 1)) & ~(RPAD - 1);  // padded slot count
    if (i < n) dis[i] = rsqrtf(1.0f + (float)c);  // self loop -> deg >= 1
    sm[threadIdx.x] = v;
    __syncthreads();
    for (int off = 1; off < 256; off <<= 1) {
        int t = (threadIdx.x >= off) ? sm[threadIdx.x - off] : 0;
        __syncthreads();
        sm[threadIdx.x] += t;
        __syncthreads();
    }
    if (i < n) row_start[i] = sm[threadIdx.x] - v;  // exclusive
    if (threadIdx.x == 255) partial[blockIdx.x] = sm[255];
}

// Single-block exclusive scan of per-block partials (P <= 1024); writes total.
__global__ void scan_partials_kernel(int* __restrict__ partial, int* __restrict__ total_out, int P) {
    __shared__ int sm[1024];
    int v = (threadIdx.x < P) ? partial[threadIdx.x] : 0;
    sm[threadIdx.x] = v;
    __syncthreads();
    for (int off = 1; off < 1024; off <<= 1) {
        int t = (threadIdx.x >= off) ? sm[threadIdx.x - off] : 0;
        __syncthreads();
        sm[threadIdx.x] += t;
        __syncthreads();
    }
    if (threadIdx.x < P) partial[threadIdx.x] = sm[threadIdx.x] - v;  // exclusive
    if (threadIdx.x == P - 1) *total_out = sm[threadIdx.x];           // row_start[n]
}

__global__ void add_offsets_kernel(int* __restrict__ row_start, const int* __restrict__ partial, int n) {
    int i = blockIdx.x * blockDim.x + threadIdx.x;
    if (i < n) row_start[i] += partial[i >> 8];
}

// Pre-fill all padded CSR slots with the dummy node id (= n, xs[n]=0).
__global__ void init_csr_kernel(int* __restrict__ csr_col, int cap, int dummy) {
    int i = blockIdx.x * blockDim.x + threadIdx.x;
    if (i < cap) csr_col[i] = dummy;
}

__global__ void fill_csr_kernel(const int* __restrict__ rows, const int* __restrict__ cols,
                                const int* __restrict__ row_start, int* __restrict__ cursor,
                                int* __restrict__ csr_col, int e) {
    int i = blockIdx.x * blockDim.x + threadIdx.x;
    if (i < e) {
        int r = rows[i];
        int pos = row_start[r] + atomicAdd(&cursor[r], 1);
        csr_col[pos] = cols[i];
    }
}

// xs0[i,:] = dis[i] * x[i,:] ; dummy row n is zeroed.
__global__ void scale_x_kernel(const float* __restrict__ x, const float* __restrict__ dis,
                               float* __restrict__ xs, int n) {
    int i = blockIdx.x * blockDim.x + threadIdx.x;  // over (n+1)*16 float4s
    int total = (n + 1) * (D_FEAT / 4);
    if (i >= total) return;
    int node = i >> 4;
    if (node < n) {
        float s = dis[node];
        float4 v = ((const float4*)x)[i];
        v.x *= s; v.y *= s; v.z *= s; v.w *= s;
        ((float4*)xs)[i] = v;
    } else {
        ((float4*)xs)[i] = make_float4(0.f, 0.f, 0.f, 0.f);
    }
}

// Hop 1: xs1[r,:] = dis[r]^2 * ( xs0[r,:] + sum_c xs0[c,:] ).
// One wave per row; rows padded to multiple of 8 -> branch-free unroll x8.
__global__ __launch_bounds__(256) void spmm_scaled_kernel(const float* __restrict__ xs_in,
                                                          float* __restrict__ xs_out,
                                                          const int* __restrict__ row_start,
                                                          const int* __restrict__ csr_col,
                                                          const float* __restrict__ dis, int n) {
    int wave = (blockIdx.x * blockDim.x + threadIdx.x) >> 6;
    int lane = threadIdx.x & 63;
    if (wave > n) return;
    if (wave == n) { xs_out[n * D_FEAT + lane] = 0.f; return; }  // dummy row for hop 2
    int r = wave;
    int s = row_start[r], t = row_start[r + 1];
    float a0 = 0.f, a1 = 0.f, a2 = 0.f, a3 = 0.f, a4 = 0.f, a5 = 0.f, a6 = 0.f, a7 = 0.f;
    for (int j = s; j < t; j += 8) {
        int c0 = csr_col[j + 0], c1 = csr_col[j + 1], c2 = csr_col[j + 2], c3 = csr_col[j + 3];
        int c4 = csr_col[j + 4], c5 = csr_col[j + 5], c6 = csr_col[j + 6], c7 = csr_col[j + 7];
        a0 += xs_in[c0 * D_FEAT + lane];
        a1 += xs_in[c1 * D_FEAT + lane];
        a2 += xs_in[c2 * D_FEAT + lane];
        a3 += xs_in[c3 * D_FEAT + lane];
        a4 += xs_in[c4 * D_FEAT + lane];
        a5 += xs_in[c5 * D_FEAT + lane];
        a6 += xs_in[c6 * D_FEAT + lane];
        a7 += xs_in[c7 * D_FEAT + lane];
    }
    float dr = dis[r];
    float sum = ((a0 + a1) + (a2 + a3)) + ((a4 + a5) + (a6 + a7)) + xs_in[r * D_FEAT + lane];
    xs_out[r * D_FEAT + lane] = dr * dr * sum;
}

// Hop 2 fused with logits + log_softmax. h2[r,:] = dis[r]*(xs1[r,:]+sum_c xs1[c,:]).
__global__ __launch_bounds__(256) void spmm_logits_kernel(const float* __restrict__ xs_in,
                                                          const int* __restrict__ row_start,
                                                          const int* __restrict__ csr_col,
                                                          const float* __restrict__ dis,
                                                          const float* __restrict__ W,
                                                          const float* __restrict__ b,
                                                          float* __restrict__ out, int n) {
    __shared__ float Wl[D_FEAT * NCLS];
    __shared__ float bl[NCLS];
    for (int i = threadIdx.x; i < D_FEAT * NCLS; i += blockDim.x) Wl[i] = W[i];
    for (int i = threadIdx.x; i < NCLS; i += blockDim.x) bl[i] = b[i];
    __syncthreads();

    int wave = (blockIdx.x * blockDim.x + threadIdx.x) >> 6;
    int lane = threadIdx.x & 63;
    if (wave >= n) return;
    int r = wave;
    int s = row_start[r], t = row_start[r + 1];
    float a0 = 0.f, a1 = 0.f, a2 = 0.f, a3 = 0.f, a4 = 0.f, a5 = 0.f, a6 = 0.f, a7 = 0.f;
    for (int j = s; j < t; j += 8) {
        int c0 = csr_col[j + 0], c1 = csr_col[j + 1], c2 = csr_col[j + 2], c3 = csr_col[j + 3];
        int c4 = csr_col[j + 4], c5 = csr_col[j + 5], c6 = csr_col[j + 6], c7 = csr_col[j + 7];
        a0 += xs_in[c0 * D_FEAT + lane];
        a1 += xs_in[c1 * D_FEAT + lane];
        a2 += xs_in[c2 * D_FEAT + lane];
        a3 += xs_in[c3 * D_FEAT + lane];
        a4 += xs_in[c4 * D_FEAT + lane];
        a5 += xs_in[c5 * D_FEAT + lane];
        a6 += xs_in[c6 * D_FEAT + lane];
        a7 += xs_in[c7 * D_FEAT + lane];
    }
    float sum = ((a0 + a1) + (a2 + a3)) + ((a4 + a5) + (a6 + a7)) + xs_in[r * D_FEAT + lane];
    float h = dis[r] * sum;  // final hop-2 feature d=lane of row r

    // GEMV: y[c] = b[c] + sum_d h_d * W[d,c]. Lanes >= NCLS duplicate lane-NCLS's
    // address (broadcast pairs -> no LDS bank conflicts).
    int wl = (lane < NCLS) ? lane : (lane - NCLS);
    float yv = bl[wl];
#pragma unroll
    for (int d = 0; d < D_FEAT; d++) {
        float xv = __shfl(h, d, 64);
        yv += xv * Wl[d * NCLS + wl];
    }
    float y = (lane < NCLS) ? yv : -INFINITY;

    // wave-wide log_softmax over the 40 valid lanes
    float m = y;
#pragma unroll
    for (int o = 32; o > 0; o >>= 1) m = fmaxf(m, __shfl_xor(m, o, 64));
    float sfull = __expf(y - m);  // lanes >= 40: exp(-inf) = 0
#pragma unroll
    for (int o = 32; o > 0; o >>= 1) sfull += __shfl_xor(sfull, o, 64);
    float lse = m + __logf(sfull);

    if (lane < NCLS) out[r * NCLS + lane] = y - lse;
}

extern "C" void kernel_launch(void* const* d_in, const int* in_sizes, int n_in,
                              void* d_out, int out_size, void* d_ws, size_t ws_size,
                              hipStream_t stream) {
    const float* x  = (const float*)d_in[0];
    const int*   ei = (const int*)d_in[1];   // [2, E] flat: rows then cols (int32)
    const float* W  = (const float*)d_in[2]; // [64, 40]
    const float* b  = (const float*)d_in[3]; // [40]
    float* out = (float*)d_out;

    const int n = in_sizes[0] / D_FEAT;      // 100000
    const int e = in_sizes[1] / 2;           // 1600000

    const int* rows = ei;
    const int* cols = ei + e;

    // workspace layout (all 256-element aligned):
    //   counts[n] | cursor[n] | row_start[n+1] | partial[P] | dis[n] |
    //   csr_col[e + (RPAD-1)*n] | xs0[(n+1)*64] | xs1[(n+1)*64]
    size_t na = ((size_t)n + 256) & ~(size_t)255;
    int*   counts    = (int*)d_ws;
    int*   cursor    = counts + na;
    int*   row_start = cursor + na;
    int    P         = (n + 255) / 256;
    int*   partial   = row_start + na;
    float* dis       = (float*)(partial + (((size_t)P + 255) & ~(size_t)255));
    int    csr_cap   = e + (RPAD - 1) * n;
    int*   csr_col   = (int*)(dis + na);
    float* xs0       = (float*)(csr_col + (((size_t)csr_cap + 255) & ~(size_t)255));
    float* xs1       = xs0 + (size_t)(n + 1) * D_FEAT;

    const int BS = 256;

    zero_ints_kernel<<<(n + BS - 1) / BS, BS, 0, stream>>>(counts, cursor, n);
    count_rows_kernel<<<(e + BS - 1) / BS, BS, 0, stream>>>(rows, counts, e);
    scan_blocks_kernel<<<P, BS, 0, stream>>>(counts, row_start, partial, dis, n);
    scan_partials_kernel<<<1, 1024, 0, stream>>>(partial, &row_start[n], P);
    add_offsets_kernel<<<(n + BS - 1) / BS, BS, 0, stream>>>(row_start, partial, n);
    init_csr_kernel<<<(csr_cap + BS - 1) / BS, BS, 0, stream>>>(csr_col, csr_cap, n);
    fill_csr_kernel<<<(e + BS - 1) / BS, BS, 0, stream>>>(rows, cols, row_start, cursor, csr_col, e);
    {
        int tot = (n + 1) * (D_FEAT / 4);
        scale_x_kernel<<<(tot + BS - 1) / BS, BS, 0, stream>>>(x, dis, xs0, n);
    }

    int blocks1 = (n + 1 + 3) / 4;  // n+1 waves (incl. dummy-row writer)
    spmm_scaled_kernel<<<blocks1, BS, 0, stream>>>(xs0, xs1, row_start, csr_col, dis, n);
    int blocks2 = (n + 3) / 4;
    spmm_logits_kernel<<<blocks2, BS, 0, stream>>>(xs1, row_start, csr_col, dis, W, b, out, n);
}

// Round 4
// 418.717 us; speedup vs baseline: 2.1891x; 1.0612x over previous
//
#include <hip/hip_runtime.h>
#include <math.h>

// SGC: K=2 hops of D^-1/2 (A+I) D^-1/2, then x@W+b, then log_softmax.
// N=100000, D=64, C=40, E=1600000.
//
// R4 strategy: CSR gather-SpMM with PACKED BF16 intermediates.
// - xs rows are 64 bf16 = 128 B = 32 dwords. A half-wave (32 lanes) gathers a
//   full neighbor row, so one wave vmem instruction covers TWO neighbors.
//   Unroll x8 -> 16 neighbors in flight per wave (2x the R3 MLP) at half the
//   bytes. Working set 25.6 -> 12.8 MB (better per-XCD L2 hit rate).
// - Lane hl (0..31) accumulates features 2hl, 2hl+1; halves combine via
//   shfl_xor(32). CSR rows padded to multiple of 16 with dummy node n
//   (xs[n] = 0, its two 64B lines stay cache-hot).
// - Hop 2 fused with 64x40 GEMV (shfl broadcast vs LDS W) + log_softmax.

#define D_FEAT 64
#define NCLS 40
#define RPAD 16  // row padding multiple (= 2 neighbors x 8 unroll)

__device__ __forceinline__ unsigned pack_bf16_2(float lo, float hi) {
    unsigned ulo = __float_as_uint(lo);
    unsigned uhi = __float_as_uint(hi);
    ulo = (ulo + 0x7fffu + ((ulo >> 16) & 1u)) >> 16;           // RNE
    uhi = (uhi + 0x7fffu + ((uhi >> 16) & 1u)) & 0xffff0000u;   // RNE
    return uhi | ulo;
}

__global__ void zero_ints_kernel(int* __restrict__ a, int* __restrict__ b, int n) {
    int i = blockIdx.x * blockDim.x + threadIdx.x;
    if (i < n) { a[i] = 0; b[i] = 0; }
}

__global__ void count_rows_kernel(const int* __restrict__ rows, int* __restrict__ counts, int e) {
    int i = blockIdx.x * blockDim.x + threadIdx.x;
    if (i < e) atomicAdd(&counts[rows[i]], 1);
}

// Per-256-block exclusive scan of PADDED counts; also emits dis = rsqrt(1+deg).
__global__ void scan_blocks_kernel(const int* __restrict__ counts, int* __restrict__ row_start,
                                   int* __restrict__ partial, float* __restrict__ dis, int n) {
    __shared__ int sm[256];
    int i = blockIdx.x * 256 + threadIdx.x;
    int c = (i < n) ? counts[i] : 0;
    int v = (c + (RPAD - 1)) & ~(RPAD - 1);  // padded slot count
    if (i < n) dis[i] = rsqrtf(1.0f + (float)c);  // self loop -> deg >= 1
    sm[threadIdx.x] = v;
    __syncthreads();
    for (int off = 1; off < 256; off <<= 1) {
        int t = (threadIdx.x >= off) ? sm[threadIdx.x - off] : 0;
        __syncthreads();
        sm[threadIdx.x] += t;
        __syncthreads();
    }
    if (i < n) row_start[i] = sm[threadIdx.x] - v;  // exclusive
    if (threadIdx.x == 255) partial[blockIdx.x] = sm[255];
}

// Single-block exclusive scan of per-block partials (P <= 1024); writes total.
__global__ void scan_partials_kernel(int* __restrict__ partial, int* __restrict__ total_out, int P) {
    __shared__ int sm[1024];
    int v = (threadIdx.x < P) ? partial[threadIdx.x] : 0;
    sm[threadIdx.x] = v;
    __syncthreads();
    for (int off = 1; off < 1024; off <<= 1) {
        int t = (threadIdx.x >= off) ? sm[threadIdx.x - off] : 0;
        __syncthreads();
        sm[threadIdx.x] += t;
        __syncthreads();
    }
    if (threadIdx.x < P) partial[threadIdx.x] = sm[threadIdx.x] - v;  // exclusive
    if (threadIdx.x == P - 1) *total_out = sm[threadIdx.x];           // row_start[n]
}

__global__ void add_offsets_kernel(int* __restrict__ row_start, const int* __restrict__ partial, int n) {
    int i = blockIdx.x * blockDim.x + threadIdx.x;
    if (i < n) row_start[i] += partial[i >> 8];
}

// Pre-fill all padded CSR slots with the dummy node id (= n, xs[n]=0).
__global__ void init_csr_kernel(int* __restrict__ csr_col, int cap, int dummy) {
    int i = blockIdx.x * blockDim.x + threadIdx.x;
    if (i < cap) csr_col[i] = dummy;
}

__global__ void fill_csr_kernel(const int* __restrict__ rows, const int* __restrict__ cols,
                                const int* __restrict__ row_start, int* __restrict__ cursor,
                                int* __restrict__ csr_col, int e) {
    int i = blockIdx.x * blockDim.x + threadIdx.x;
    if (i < e) {
        int r = rows[i];
        int pos = row_start[r] + atomicAdd(&cursor[r], 1);
        csr_col[pos] = cols[i];
    }
}

// xs0[i] = bf16(dis[i] * x[i,:]) packed 2-per-dword; dummy row n zeroed.
// One thread per dword: reads float2, writes packed uint.
__global__ void scale_x_kernel(const float* __restrict__ x, const float* __restrict__ dis,
                               unsigned* __restrict__ xsh, int n) {
    int i = blockIdx.x * blockDim.x + threadIdx.x;  // over (n+1)*32 dwords
    int total = (n + 1) * (D_FEAT / 2);
    if (i >= total) return;
    int node = i >> 5;
    if (node < n) {
        float s = dis[node];
        float2 v = ((const float2*)x)[i];
        xsh[i] = pack_bf16_2(s * v.x, s * v.y);
    } else {
        xsh[i] = 0u;
    }
}

// Hop 1: xs1[r,:] = bf16( dis[r]^2 * ( xs0[r,:] + sum_c xs0[c,:] ) ).
// One wave per row; half-wave gathers one 128B bf16 row; unroll x8 = 16
// neighbors in flight. Lane hl accumulates features 2hl, 2hl+1.
__global__ __launch_bounds__(256) void spmm_hop1_kernel(const unsigned* __restrict__ xs_in,
                                                        unsigned* __restrict__ xs_out,
                                                        const int* __restrict__ row_start,
                                                        const int* __restrict__ csr_col,
                                                        const float* __restrict__ dis, int n) {
    int wave = (blockIdx.x * blockDim.x + threadIdx.x) >> 6;
    int lane = threadIdx.x & 63;
    int half = lane >> 5, hl = lane & 31;
    if (wave > n) return;
    if (wave == n) {  // write dummy row of xs_out for hop 2
        if (half == 0) xs_out[n * 32 + hl] = 0u;
        return;
    }
    int r = wave;
    int s = row_start[r], t = row_start[r + 1];
    float p0 = 0.f, q0 = 0.f, p1 = 0.f, q1 = 0.f, p2 = 0.f, q2 = 0.f, p3 = 0.f, q3 = 0.f;
    float p4 = 0.f, q4 = 0.f, p5 = 0.f, q5 = 0.f, p6 = 0.f, q6 = 0.f, p7 = 0.f, q7 = 0.f;
    for (int j = s; j < t; j += 16) {
        int c0 = csr_col[j + 0 + half], c1 = csr_col[j + 2 + half];
        int c2 = csr_col[j + 4 + half], c3 = csr_col[j + 6 + half];
        int c4 = csr_col[j + 8 + half], c5 = csr_col[j + 10 + half];
        int c6 = csr_col[j + 12 + half], c7 = csr_col[j + 14 + half];
        unsigned u0 = xs_in[c0 * 32 + hl], u1 = xs_in[c1 * 32 + hl];
        unsigned u2 = xs_in[c2 * 32 + hl], u3 = xs_in[c3 * 32 + hl];
        unsigned u4 = xs_in[c4 * 32 + hl], u5 = xs_in[c5 * 32 + hl];
        unsigned u6 = xs_in[c6 * 32 + hl], u7 = xs_in[c7 * 32 + hl];
        p0 += __uint_as_float(u0 << 16); q0 += __uint_as_float(u0 & 0xffff0000u);
        p1 += __uint_as_float(u1 << 16); q1 += __uint_as_float(u1 & 0xffff0000u);
        p2 += __uint_as_float(u2 << 16); q2 += __uint_as_float(u2 & 0xffff0000u);
        p3 += __uint_as_float(u3 << 16); q3 += __uint_as_float(u3 & 0xffff0000u);
        p4 += __uint_as_float(u4 << 16); q4 += __uint_as_float(u4 & 0xffff0000u);
        p5 += __uint_as_float(u5 << 16); q5 += __uint_as_float(u5 & 0xffff0000u);
        p6 += __uint_as_float(u6 << 16); q6 += __uint_as_float(u6 & 0xffff0000u);
        p7 += __uint_as_float(u7 << 16); q7 += __uint_as_float(u7 & 0xffff0000u);
    }
    float se = ((p0 + p1) + (p2 + p3)) + ((p4 + p5) + (p6 + p7));  // even feature 2hl
    float so = ((q0 + q1) + (q2 + q3)) + ((q4 + q5) + (q6 + q7));  // odd feature 2hl+1
    se += __shfl_xor(se, 32, 64);
    so += __shfl_xor(so, 32, 64);
    unsigned us = xs_in[r * 32 + hl];  // self term (same word both halves)
    se += __uint_as_float(us << 16);
    so += __uint_as_float(us & 0xffff0000u);
    float dr = dis[r];
    float dr2 = dr * dr;
    if (half == 0) xs_out[r * 32 + hl] = pack_bf16_2(dr2 * se, dr2 * so);
}

// Hop 2 fused with logits + log_softmax. h2[r,:] = dis[r]*(xs1[r,:]+sum_c xs1[c,:]).
__global__ __launch_bounds__(256) void spmm_logits_kernel(const unsigned* __restrict__ xs_in,
                                                          const int* __restrict__ row_start,
                                                          const int* __restrict__ csr_col,
                                                          const float* __restrict__ dis,
                                                          const float* __restrict__ W,
                                                          const float* __restrict__ b,
                                                          float* __restrict__ out, int n) {
    __shared__ float Wl[D_FEAT * NCLS];
    __shared__ float bl[NCLS];
    for (int i = threadIdx.x; i < D_FEAT * NCLS; i += blockDim.x) Wl[i] = W[i];
    for (int i = threadIdx.x; i < NCLS; i += blockDim.x) bl[i] = b[i];
    __syncthreads();

    int wave = (blockIdx.x * blockDim.x + threadIdx.x) >> 6;
    int lane = threadIdx.x & 63;
    int half = lane >> 5, hl = lane & 31;
    if (wave >= n) return;
    int r = wave;
    int s = row_start[r], t = row_start[r + 1];
    float p0 = 0.f, q0 = 0.f, p1 = 0.f, q1 = 0.f, p2 = 0.f, q2 = 0.f, p3 = 0.f, q3 = 0.f;
    float p4 = 0.f, q4 = 0.f, p5 = 0.f, q5 = 0.f, p6 = 0.f, q6 = 0.f, p7 = 0.f, q7 = 0.f;
    for (int j = s; j < t; j += 16) {
        int c0 = csr_col[j + 0 + half], c1 = csr_col[j + 2 + half];
        int c2 = csr_col[j + 4 + half], c3 = csr_col[j + 6 + half];
        int c4 = csr_col[j + 8 + half], c5 = csr_col[j + 10 + half];
        int c6 = csr_col[j + 12 + half], c7 = csr_col[j + 14 + half];
        unsigned u0 = xs_in[c0 * 32 + hl], u1 = xs_in[c1 * 32 + hl];
        unsigned u2 = xs_in[c2 * 32 + hl], u3 = xs_in[c3 * 32 + hl];
        unsigned u4 = xs_in[c4 * 32 + hl], u5 = xs_in[c5 * 32 + hl];
        unsigned u6 = xs_in[c6 * 32 + hl], u7 = xs_in[c7 * 32 + hl];
        p0 += __uint_as_float(u0 << 16); q0 += __uint_as_float(u0 & 0xffff0000u);
        p1 += __uint_as_float(u1 << 16); q1 += __uint_as_float(u1 & 0xffff0000u);
        p2 += __uint_as_float(u2 << 16); q2 += __uint_as_float(u2 & 0xffff0000u);
        p3 += __uint_as_float(u3 << 16); q3 += __uint_as_float(u3 & 0xffff0000u);
        p4 += __uint_as_float(u4 << 16); q4 += __uint_as_float(u4 & 0xffff0000u);
        p5 += __uint_as_float(u5 << 16); q5 += __uint_as_float(u5 & 0xffff0000u);
        p6 += __uint_as_float(u6 << 16); q6 += __uint_as_float(u6 & 0xffff0000u);
        p7 += __uint_as_float(u7 << 16); q7 += __uint_as_float(u7 & 0xffff0000u);
    }
    float se = ((p0 + p1) + (p2 + p3)) + ((p4 + p5) + (p6 + p7));
    float so = ((q0 + q1) + (q2 + q3)) + ((q4 + q5) + (q6 + q7));
    se += __shfl_xor(se, 32, 64);
    so += __shfl_xor(so, 32, 64);
    unsigned us = xs_in[r * 32 + hl];
    se += __uint_as_float(us << 16);
    so += __uint_as_float(us & 0xffff0000u);
    float dr = dis[r];
    float he = dr * se;  // feature 2hl of final h2 (both halves hold copies)
    float ho = dr * so;  // feature 2hl+1

    // GEMV: y[c] = b[c] + sum_d h_d W[d,c]. Feature 2w lives in lane w's `he`,
    // 2w+1 in lane w's `ho` (w = 0..31, both halves identical -> shfl from lane w).
    int wl = (lane < NCLS) ? lane : (lane - NCLS);  // dup addrs = broadcast, no conflicts
    float yv = bl[wl];
#pragma unroll
    for (int w = 0; w < 32; w++) {
        float xe = __shfl(he, w, 64);
        float xo = __shfl(ho, w, 64);
        yv += xe * Wl[(2 * w) * NCLS + wl];
        yv += xo * Wl[(2 * w + 1) * NCLS + wl];
    }
    float y = (lane < NCLS) ? yv : -INFINITY;

    // wave-wide log_softmax over the 40 valid lanes
    float m = y;
#pragma unroll
    for (int o = 32; o > 0; o >>= 1) m = fmaxf(m, __shfl_xor(m, o, 64));
    float sfull = __expf(y - m);  // lanes >= 40: exp(-inf) = 0
#pragma unroll
    for (int o = 32; o > 0; o >>= 1) sfull += __shfl_xor(sfull, o, 64);
    float lse = m + __logf(sfull);

    if (lane < NCLS) out[r * NCLS + lane] = y - lse;
}

extern "C" void kernel_launch(void* const* d_in, const int* in_sizes, int n_in,
                              void* d_out, int out_size, void* d_ws, size_t ws_size,
                              hipStream_t stream) {
    const float* x  = (const float*)d_in[0];
    const int*   ei = (const int*)d_in[1];   // [2, E] flat: rows then cols (int32)
    const float* W  = (const float*)d_in[2]; // [64, 40]
    const float* b  = (const float*)d_in[3]; // [40]
    float* out = (float*)d_out;

    const int n = in_sizes[0] / D_FEAT;      // 100000
    const int e = in_sizes[1] / 2;           // 1600000

    const int* rows = ei;
    const int* cols = ei + e;

    // workspace layout (all 256-element aligned):
    //   counts[n] | cursor[n] | row_start[n+1] | partial[P] | dis[n] |
    //   csr_col[e + (RPAD-1)*n] | xs0h[(n+1)*32] | xs1h[(n+1)*32]
    size_t na = ((size_t)n + 256) & ~(size_t)255;
    int*      counts    = (int*)d_ws;
    int*      cursor    = counts + na;
    int*      row_start = cursor + na;
    int       P         = (n + 255) / 256;
    int*      partial   = row_start + na;
    float*    dis       = (float*)(partial + (((size_t)P + 255) & ~(size_t)255));
    int       csr_cap   = e + (RPAD - 1) * n;
    int*      csr_col   = (int*)(dis + na);
    unsigned* xs0h      = (unsigned*)(csr_col + (((size_t)csr_cap + 255) & ~(size_t)255));
    unsigned* xs1h      = xs0h + (size_t)(n + 1) * (D_FEAT / 2);

    const int BS = 256;

    zero_ints_kernel<<<(n + BS - 1) / BS, BS, 0, stream>>>(counts, cursor, n);
    count_rows_kernel<<<(e + BS - 1) / BS, BS, 0, stream>>>(rows, counts, e);
    scan_blocks_kernel<<<P, BS, 0, stream>>>(counts, row_start, partial, dis, n);
    scan_partials_kernel<<<1, 1024, 0, stream>>>(partial, &row_start[n], P);
    add_offsets_kernel<<<(n + BS - 1) / BS, BS, 0, stream>>>(row_start, partial, n);
    init_csr_kernel<<<(csr_cap + BS - 1) / BS, BS, 0, stream>>>(csr_col, csr_cap, n);
    fill_csr_kernel<<<(e + BS - 1) / BS, BS, 0, stream>>>(rows, cols, row_start, cursor, csr_col, e);
    {
        int tot = (n + 1) * (D_FEAT / 2);
        scale_x_kernel<<<(tot + BS - 1) / BS, BS, 0, stream>>>(x, dis, xs0h, n);
    }

    int blocks1 = (n + 1 + 3) / 4;  // n+1 waves (incl. dummy-row writer)
    spmm_hop1_kernel<<<blocks1, BS, 0, stream>>>(xs0h, xs1h, row_start, csr_col, dis, n);
    int blocks2 = (n + 3) / 4;
    spmm_logits_kernel<<<blocks2, BS, 0, stream>>>(xs1h, row_start, csr_col, dis, W, b, out, n);
}

// Round 5
// 359.027 us; speedup vs baseline: 2.5530x; 1.1663x over previous
//
#include <hip/hip_runtime.h>
#include <math.h>

// SGC: K=2 hops of D^-1/2 (A+I) D^-1/2, then x@W+b, then log_softmax.
// N=100000, D=64, C=40, E=1600000.
//
// R5 strategy: quarter-wave-per-row CSR gather-SpMM, bf16 intermediates.
// - A bf16 row is 64 bf16 = 128 B = 16 uint2. A quarter-wave (16 lanes, uint2
//   per lane) gathers one full neighbor row -> one vmem instruction covers 4
//   neighbors (one per quarter). Wave owns 4 consecutive rows.
// - CSR rows padded to multiple of 4 only (avg slots/row ~17.5 vs ~24 at
//   pad-16): ~27% fewer 64B line fills (the real limiter: line-fill
//   concurrency per CU, not bandwidth -- HBM 9.5%, L2 2.2 TB/s in R4).
// - 2 predicated 4-neighbor groups per iteration, loads into zero-init regs,
//   unconditional accumulate -> 8 gather insts = 32 slots in flight per wave.
// - csr ids loaded as one uint4 per quarter per group.
// - Hop 2 fused with 64x40 GEMV (per-lane-src shfl broadcast within quarter,
//   lane covers <=3 classes) + log_softmax.

#define D_FEAT 64
#define NCLS 40
#define RPAD 4   // row padding multiple

__device__ __forceinline__ unsigned pack_bf16_2(float lo, float hi) {
    unsigned ulo = __float_as_uint(lo);
    unsigned uhi = __float_as_uint(hi);
    ulo = (ulo + 0x7fffu + ((ulo >> 16) & 1u)) >> 16;           // RNE
    uhi = (uhi + 0x7fffu + ((uhi >> 16) & 1u)) & 0xffff0000u;   // RNE
    return uhi | ulo;
}

__device__ __forceinline__ void acc2(unsigned u, float& a, float& b) {
    a += __uint_as_float(u << 16);
    b += __uint_as_float(u & 0xffff0000u);
}

__global__ void zero_ints_kernel(int* __restrict__ a, int* __restrict__ b, int n) {
    int i = blockIdx.x * blockDim.x + threadIdx.x;
    if (i < n) { a[i] = 0; b[i] = 0; }
}

__global__ void count_rows_kernel(const int* __restrict__ rows, int* __restrict__ counts, int e) {
    int i = blockIdx.x * blockDim.x + threadIdx.x;
    if (i < e) atomicAdd(&counts[rows[i]], 1);
}

// Per-256-block exclusive scan of PADDED counts; also emits dis = rsqrt(1+deg).
__global__ void scan_blocks_kernel(const int* __restrict__ counts, int* __restrict__ row_start,
                                   int* __restrict__ partial, float* __restrict__ dis, int n) {
    __shared__ int sm[256];
    int i = blockIdx.x * 256 + threadIdx.x;
    int c = (i < n) ? counts[i] : 0;
    int v = (c + (RPAD - 1)) & ~(RPAD - 1);  // padded slot count
    if (i < n) dis[i] = rsqrtf(1.0f + (float)c);  // self loop -> deg >= 1
    sm[threadIdx.x] = v;
    __syncthreads();
    for (int off = 1; off < 256; off <<= 1) {
        int t = (threadIdx.x >= off) ? sm[threadIdx.x - off] : 0;
        __syncthreads();
        sm[threadIdx.x] += t;
        __syncthreads();
    }
    if (i < n) row_start[i] = sm[threadIdx.x] - v;  // exclusive
    if (threadIdx.x == 255) partial[blockIdx.x] = sm[255];
}

// Single-block exclusive scan of per-block partials (P <= 1024); writes total.
__global__ void scan_partials_kernel(int* __restrict__ partial, int* __restrict__ total_out, int P) {
    __shared__ int sm[1024];
    int v = (threadIdx.x < P) ? partial[threadIdx.x] : 0;
    sm[threadIdx.x] = v;
    __syncthreads();
    for (int off = 1; off < 1024; off <<= 1) {
        int t = (threadIdx.x >= off) ? sm[threadIdx.x - off] : 0;
        __syncthreads();
        sm[threadIdx.x] += t;
        __syncthreads();
    }
    if (threadIdx.x < P) partial[threadIdx.x] = sm[threadIdx.x] - v;  // exclusive
    if (threadIdx.x == P - 1) *total_out = sm[threadIdx.x];           // row_start[n]
}

__global__ void add_offsets_kernel(int* __restrict__ row_start, const int* __restrict__ partial, int n) {
    int i = blockIdx.x * blockDim.x + threadIdx.x;
    if (i < n) row_start[i] += partial[i >> 8];
}

// Pre-fill all padded CSR slots with the dummy node id (= n, xs[n]=0).
__global__ void init_csr_kernel(int* __restrict__ csr_col, int cap, int dummy) {
    int i = blockIdx.x * blockDim.x + threadIdx.x;
    if (i < cap) csr_col[i] = dummy;
}

__global__ void fill_csr_kernel(const int* __restrict__ rows, const int* __restrict__ cols,
                                const int* __restrict__ row_start, int* __restrict__ cursor,
                                int* __restrict__ csr_col, int e) {
    int i = blockIdx.x * blockDim.x + threadIdx.x;
    if (i < e) {
        int r = rows[i];
        int pos = row_start[r] + atomicAdd(&cursor[r], 1);
        csr_col[pos] = cols[i];
    }
}

// xs0[i] = bf16(dis[i] * x[i,:]) packed 2/dword; dummy rows (n) of BOTH xs
// arrays zeroed (hop1 never writes xs1 row n; hop2 gathers it for pad slots).
__global__ void scale_x_kernel(const float* __restrict__ x, const float* __restrict__ dis,
                               unsigned* __restrict__ xs0, unsigned* __restrict__ xs1, int n) {
    int i = blockIdx.x * blockDim.x + threadIdx.x;  // over (n+1)*32 dwords
    int total = (n + 1) * (D_FEAT / 2);
    if (i >= total) return;
    int node = i >> 5;
    if (node < n) {
        float s = dis[node];
        float2 v = ((const float2*)x)[i];
        xs0[i] = pack_bf16_2(s * v.x, s * v.y);
    } else {
        xs0[i] = 0u;
        xs1[i] = 0u;  // dummy row of hop-1 output
    }
}

// Hop 1: xs1[r,:] = bf16( dis[r]^2 * ( xs0[r,:] + sum_c xs0[c,:] ) ).
// Wave owns rows 4*wave..4*wave+3; quarter q of the wave owns row 4*wave+q.
// Lane (q,ql) holds features 4ql..4ql+3 of its row in h0..h3.
__global__ __launch_bounds__(256) void spmm_hop1_kernel(const uint2* __restrict__ xs_in,
                                                        uint2* __restrict__ xs_out,
                                                        const int* __restrict__ row_start,
                                                        const int* __restrict__ csr_col,
                                                        const float* __restrict__ dis, int n) {
    int wave = (blockIdx.x * blockDim.x + threadIdx.x) >> 6;
    int lane = threadIdx.x & 63;
    int q = lane >> 4, ql = lane & 15;
    int r = wave * 4 + q;
    bool valid = r < n;
    int s = 0, len = 0;
    if (valid) { s = row_start[r]; len = row_start[r + 1] - s; }
    int maxlen = len;
    maxlen = max(maxlen, __shfl_xor(maxlen, 16, 64));
    maxlen = max(maxlen, __shfl_xor(maxlen, 32, 64));

    float h0 = 0.f, h1 = 0.f, h2 = 0.f, h3 = 0.f;
    const uint4* cp = (const uint4*)(csr_col + s);  // s is a multiple of 4
    for (int base = 0; base < maxlen; base += 8) {
        uint2 u0 = make_uint2(0u, 0u), u1 = u0, u2 = u0, u3 = u0;
        uint2 u4 = u0, u5 = u0, u6 = u0, u7 = u0;
        if (base < len) {
            uint4 cv = cp[base >> 2];
            u0 = xs_in[cv.x * 16 + ql];
            u1 = xs_in[cv.y * 16 + ql];
            u2 = xs_in[cv.z * 16 + ql];
            u3 = xs_in[cv.w * 16 + ql];
        }
        if (base + 4 < len) {
            uint4 cv = cp[(base >> 2) + 1];
            u4 = xs_in[cv.x * 16 + ql];
            u5 = xs_in[cv.y * 16 + ql];
            u6 = xs_in[cv.z * 16 + ql];
            u7 = xs_in[cv.w * 16 + ql];
        }
        acc2(u0.x, h0, h1); acc2(u0.y, h2, h3);
        acc2(u1.x, h0, h1); acc2(u1.y, h2, h3);
        acc2(u2.x, h0, h1); acc2(u2.y, h2, h3);
        acc2(u3.x, h0, h1); acc2(u3.y, h2, h3);
        acc2(u4.x, h0, h1); acc2(u4.y, h2, h3);
        acc2(u5.x, h0, h1); acc2(u5.y, h2, h3);
        acc2(u6.x, h0, h1); acc2(u6.y, h2, h3);
        acc2(u7.x, h0, h1); acc2(u7.y, h2, h3);
    }
    if (valid) {
        uint2 us = xs_in[r * 16 + ql];  // self term
        acc2(us.x, h0, h1); acc2(us.y, h2, h3);
        float dr = dis[r];
        float dr2 = dr * dr;
        xs_out[r * 16 + ql] = make_uint2(pack_bf16_2(dr2 * h0, dr2 * h1),
                                         pack_bf16_2(dr2 * h2, dr2 * h3));
    }
}

// Hop 2 fused with logits + log_softmax. h2[r,:] = dis[r]*(xs1[r,:]+sum_c xs1[c,:]).
// Quarter q owns row 4*wave+q; lane ql holds features 4ql..4ql+3. GEMV:
// lane ql covers classes ql, ql+16, and (ql<8) ql+32; features broadcast via
// per-lane-source __shfl (ds_bpermute) within the quarter.
__global__ __launch_bounds__(256) void spmm_logits_kernel(const uint2* __restrict__ xs_in,
                                                          const int* __restrict__ row_start,
                                                          const int* __restrict__ csr_col,
                                                          const float* __restrict__ dis,
                                                          const float* __restrict__ W,
                                                          const float* __restrict__ b,
                                                          float* __restrict__ out, int n) {
    __shared__ float Wl[D_FEAT * NCLS];
    __shared__ float bl[NCLS];
    for (int i = threadIdx.x; i < D_FEAT * NCLS; i += blockDim.x) Wl[i] = W[i];
    for (int i = threadIdx.x; i < NCLS; i += blockDim.x) bl[i] = b[i];
    __syncthreads();

    int wave = (blockIdx.x * blockDim.x + threadIdx.x) >> 6;
    int lane = threadIdx.x & 63;
    int q = lane >> 4, ql = lane & 15;
    int r = wave * 4 + q;
    bool valid = r < n;
    int s = 0, len = 0;
    if (valid) { s = row_start[r]; len = row_start[r + 1] - s; }
    int maxlen = len;
    maxlen = max(maxlen, __shfl_xor(maxlen, 16, 64));
    maxlen = max(maxlen, __shfl_xor(maxlen, 32, 64));

    float h0 = 0.f, h1 = 0.f, h2 = 0.f, h3 = 0.f;
    const uint4* cp = (const uint4*)(csr_col + s);
    for (int base = 0; base < maxlen; base += 8) {
        uint2 u0 = make_uint2(0u, 0u), u1 = u0, u2 = u0, u3 = u0;
        uint2 u4 = u0, u5 = u0, u6 = u0, u7 = u0;
        if (base < len) {
            uint4 cv = cp[base >> 2];
            u0 = xs_in[cv.x * 16 + ql];
            u1 = xs_in[cv.y * 16 + ql];
            u2 = xs_in[cv.z * 16 + ql];
            u3 = xs_in[cv.w * 16 + ql];
        }
        if (base + 4 < len) {
            uint4 cv = cp[(base >> 2) + 1];
            u4 = xs_in[cv.x * 16 + ql];
            u5 = xs_in[cv.y * 16 + ql];
            u6 = xs_in[cv.z * 16 + ql];
            u7 = xs_in[cv.w * 16 + ql];
        }
        acc2(u0.x, h0, h1); acc2(u0.y, h2, h3);
        acc2(u1.x, h0, h1); acc2(u1.y, h2, h3);
        acc2(u2.x, h0, h1); acc2(u2.y, h2, h3);
        acc2(u3.x, h0, h1); acc2(u3.y, h2, h3);
        acc2(u4.x, h0, h1); acc2(u4.y, h2, h3);
        acc2(u5.x, h0, h1); acc2(u5.y, h2, h3);
        acc2(u6.x, h0, h1); acc2(u6.y, h2, h3);
        acc2(u7.x, h0, h1); acc2(u7.y, h2, h3);
    }

    float y0, y1, y2;
    {
        uint2 us = valid ? xs_in[r * 16 + ql] : make_uint2(0u, 0u);  // self term
        acc2(us.x, h0, h1); acc2(us.y, h2, h3);
        float dr = valid ? dis[r] : 0.f;
        h0 *= dr; h1 *= dr; h2 *= dr; h3 *= dr;  // final hop-2 features

        int c0 = ql, c1 = ql + 16;
        int c2 = (ql < 8) ? (ql + 32) : ql;  // dup addr for invalid -> broadcast
        y0 = bl[c0]; y1 = bl[c1]; y2 = bl[c2];
        int qbase = q << 4;
#pragma unroll
        for (int d = 0; d < D_FEAT; d++) {
            int src = qbase + (d >> 2);
            float xv;
            switch (d & 3) {
                case 0: xv = __shfl(h0, src, 64); break;
                case 1: xv = __shfl(h1, src, 64); break;
                case 2: xv = __shfl(h2, src, 64); break;
                default: xv = __shfl(h3, src, 64); break;
            }
            y0 += xv * Wl[d * NCLS + c0];
            y1 += xv * Wl[d * NCLS + c1];
            y2 += xv * Wl[d * NCLS + c2];
        }
    }

    // log_softmax over the row's 40 classes, distributed 16 lanes x (2 or 3)
    bool has3 = (ql < 8);
    float m = fmaxf(y0, y1);
    if (has3) m = fmaxf(m, y2);
#pragma unroll
    for (int o = 8; o > 0; o >>= 1) m = fmaxf(m, __shfl_xor(m, o, 64));
    float sm = __expf(y0 - m) + __expf(y1 - m) + (has3 ? __expf(y2 - m) : 0.f);
#pragma unroll
    for (int o = 8; o > 0; o >>= 1) sm += __shfl_xor(sm, o, 64);
    float lse = m + __logf(sm);

    if (valid) {
        float* op = out + (long long)r * NCLS;
        op[ql] = y0 - lse;
        op[ql + 16] = y1 - lse;
        if (has3) op[ql + 32] = y2 - lse;
    }
}

extern "C" void kernel_launch(void* const* d_in, const int* in_sizes, int n_in,
                              void* d_out, int out_size, void* d_ws, size_t ws_size,
                              hipStream_t stream) {
    const float* x  = (const float*)d_in[0];
    const int*   ei = (const int*)d_in[1];   // [2, E] flat: rows then cols (int32)
    const float* W  = (const float*)d_in[2]; // [64, 40]
    const float* b  = (const float*)d_in[3]; // [40]
    float* out = (float*)d_out;

    const int n = in_sizes[0] / D_FEAT;      // 100000
    const int e = in_sizes[1] / 2;           // 1600000

    const int* rows = ei;
    const int* cols = ei + e;

    // workspace layout (all 256-element aligned):
    //   counts[n] | cursor[n] | row_start[n+1] | partial[P] | dis[n] |
    //   csr_col[e + (RPAD-1)*n] | xs0[(n+1)*32 dw] | xs1[(n+1)*32 dw]
    size_t na = ((size_t)n + 256) & ~(size_t)255;
    int*      counts    = (int*)d_ws;
    int*      cursor    = counts + na;
    int*      row_start = cursor + na;
    int       P         = (n + 255) / 256;
    int*      partial   = row_start + na;
    float*    dis       = (float*)(partial + (((size_t)P + 255) & ~(size_t)255));
    int       csr_cap   = e + (RPAD - 1) * n;
    int*      csr_col   = (int*)(dis + na);
    unsigned* xs0       = (unsigned*)(csr_col + (((size_t)csr_cap + 255) & ~(size_t)255));
    unsigned* xs1       = xs0 + (size_t)(n + 1) * (D_FEAT / 2);

    const int BS = 256;

    zero_ints_kernel<<<(n + BS - 1) / BS, BS, 0, stream>>>(counts, cursor, n);
    count_rows_kernel<<<(e + BS - 1) / BS, BS, 0, stream>>>(rows, counts, e);
    scan_blocks_kernel<<<P, BS, 0, stream>>>(counts, row_start, partial, dis, n);
    scan_partials_kernel<<<1, 1024, 0, stream>>>(partial, &row_start[n], P);
    add_offsets_kernel<<<(n + BS - 1) / BS, BS, 0, stream>>>(row_start, partial, n);
    init_csr_kernel<<<(csr_cap + BS - 1) / BS, BS, 0, stream>>>(csr_col, csr_cap, n);
    fill_csr_kernel<<<(e + BS - 1) / BS, BS, 0, stream>>>(rows, cols, row_start, cursor, csr_col, e);
    {
        int tot = (n + 1) * (D_FEAT / 2);
        scale_x_kernel<<<(tot + BS - 1) / BS, BS, 0, stream>>>(x, dis, xs0, xs1, n);
    }

    int nwaves = (n + 3) / 4;                 // 4 rows per wave
    int blocks = (nwaves * 64 + BS - 1) / BS;
    spmm_hop1_kernel<<<blocks, BS, 0, stream>>>((const uint2*)xs0, (uint2*)xs1,
                                                row_start, csr_col, dis, n);
    spmm_logits_kernel<<<blocks, BS, 0, stream>>>((const uint2*)xs1, row_start, csr_col,
                                                  dis, W, b, out, n);
}

// Round 7
// 252.989 us; speedup vs baseline: 3.6231x; 1.4191x over previous
//
#include <hip/hip_runtime.h>
#include <math.h>

// SGC: K=2 hops of D^-1/2 (A+I) D^-1/2, then x@W+b, then log_softmax.
// N=100000, D=64, C=40, E=1600000.
//
// R7: DETERMINISTIC binned CSR build. R6's post-timing failure was
// nondeterministic CSR column order (atomic scatter) perturbing fp32 sums ->
// bf16 requantization boundary flips -> absmax tail jitter across replays.
// Fix: build each bucket's CSR in LDS and SORT each row's columns (duplicate
// cols are equal values -> sorted order is a deterministic function of the
// edge multiset). Output is now bit-identical on every call.
//  - bin_edges: per-block LDS bucket counts -> 1 global atomic per
//    (block,bucket) -> packed (rloc:9|col:17) entries, contiguous runs.
//  - build_csr: one 512-thread block per bucket, all in LDS: per-row count ->
//    dis; scan (pad-4); scatter into LDS csr; per-row insertion sort;
//    dummy-pad; coalesced copy-out. row_info[r] = (abs start, padded len).
// SpMM (R5 structure): quarter-wave per row, bf16 rows (128B = 16 uint2),
// 2 predicated 4-neighbor groups -> 32 gather slots in flight per wave.
// Hop 2 fused with 64x40 GEMV + log_softmax.

#define D_FEAT 64
#define NCLS 40
#define BROWS 512       // rows per bucket
#define BROWS_LOG 9
#define BINCAP 10240    // per-bucket edge capacity (mean 8192, sd ~90)
#define CSRCAP 12288    // per-bucket csr capacity (max padded = 10240+3*512 = 11776)
#define EPT 10          // edges per thread in bin_edges

__device__ __forceinline__ unsigned pack_bf16_2(float lo, float hi) {
    unsigned ulo = __float_as_uint(lo);
    unsigned uhi = __float_as_uint(hi);
    ulo = (ulo + 0x7fffu + ((ulo >> 16) & 1u)) >> 16;           // RNE
    uhi = (uhi + 0x7fffu + ((uhi >> 16) & 1u)) & 0xffff0000u;   // RNE
    return uhi | ulo;
}

__device__ __forceinline__ void acc2(unsigned u, float& a, float& b) {
    a += __uint_as_float(u << 16);
    b += __uint_as_float(u & 0xffff0000u);
}

__global__ void zero_cursors_kernel(int* __restrict__ cur, int nb) {
    int i = blockIdx.x * blockDim.x + threadIdx.x;
    if (i < nb) cur[i] = 0;
}

// Bin edges into per-bucket regions. Packed entry: (row&511)<<17 | col.
// (Requires n <= 131072 so col fits 17 bits; n = 100000 here.)
__global__ __launch_bounds__(256) void bin_edges_kernel(const int* __restrict__ rows,
                                                        const int* __restrict__ cols,
                                                        int* __restrict__ bucket_cursor,
                                                        unsigned* __restrict__ bins,
                                                        int e, int nb) {
    __shared__ int cnt[512];
    for (int i = threadIdx.x; i < nb; i += 256) cnt[i] = 0;
    __syncthreads();
    int base = blockIdx.x * (256 * EPT) + threadIdx.x;
    int rr[EPT], cc[EPT];
#pragma unroll
    for (int k = 0; k < EPT; k++) {
        int idx = base + k * 256;
        if (idx < e) { rr[k] = rows[idx]; cc[k] = cols[idx]; }
        else { rr[k] = -1; cc[k] = 0; }
    }
#pragma unroll
    for (int k = 0; k < EPT; k++)
        if (rr[k] >= 0) atomicAdd(&cnt[rr[k] >> BROWS_LOG], 1);
    __syncthreads();
    for (int i = threadIdx.x; i < nb; i += 256) {
        int c = cnt[i];
        cnt[i] = (c > 0) ? atomicAdd(&bucket_cursor[i], c) : 0;  // global base
    }
    __syncthreads();
#pragma unroll
    for (int k = 0; k < EPT; k++) {
        if (rr[k] >= 0) {
            int b = rr[k] >> BROWS_LOG;
            int pos = atomicAdd(&cnt[b], 1);  // absolute pos within bucket
            bins[(size_t)b * BINCAP + pos] =
                ((unsigned)(rr[k] & (BROWS - 1)) << 17) | (unsigned)cc[k];
        }
    }
}

// One 512-thread block per bucket, all staged in LDS. Emits sorted,
// dummy-padded CSR (deterministic) + row_info + dis.
__global__ __launch_bounds__(512) void build_csr_kernel(const unsigned* __restrict__ bins,
                                                        const int* __restrict__ bucket_cursor,
                                                        int* __restrict__ csr_col,
                                                        uint2* __restrict__ row_info,
                                                        float* __restrict__ dis, int n) {
    __shared__ int cnt[512];
    __shared__ int sm[512];
    __shared__ int cur[512];
    __shared__ int lcsr[CSRCAP];  // 48 KB; total static LDS = 54 KB
    int b = blockIdx.x;
    int tid = threadIdx.x;
    int m = bucket_cursor[b];
    cnt[tid] = 0;
    __syncthreads();
    const unsigned* bp = bins + (size_t)b * BINCAP;
    for (int i = tid; i < m; i += 512) atomicAdd(&cnt[bp[i] >> 17], 1);
    __syncthreads();
    int c = cnt[tid];
    int padded = (c + 3) & ~3;
    int r = b * BROWS + tid;
    if (r < n) dis[r] = rsqrtf(1.0f + (float)c);
    sm[tid] = padded;
    __syncthreads();
    for (int off = 1; off < 512; off <<= 1) {
        int t = (tid >= off) ? sm[tid - off] : 0;
        __syncthreads();
        sm[tid] += t;
        __syncthreads();
    }
    int off0 = sm[tid] - padded;  // exclusive scan
    cur[tid] = off0;
    if (r < n) row_info[r] = make_uint2((unsigned)(b * CSRCAP + off0), (unsigned)padded);
    __syncthreads();
    for (int i = tid; i < m; i += 512) {
        unsigned u = bp[i];
        int pos = atomicAdd(&cur[u >> 17], 1);
        lcsr[pos] = (int)(u & 0x1FFFFu);
    }
    __syncthreads();
    // Per-row insertion sort (determinism: sorted multiset order) + dummy pad.
    for (int i2 = off0 + 1; i2 < off0 + c; i2++) {
        int key = lcsr[i2];
        int j = i2 - 1;
        while (j >= off0 && lcsr[j] > key) { lcsr[j + 1] = lcsr[j]; j--; }
        lcsr[j + 1] = key;
    }
    for (int j = off0 + c; j < off0 + padded; j++) lcsr[j] = n;
    __syncthreads();
    int tot = sm[511];  // total padded slots in this bucket
    int* cp = csr_col + (size_t)b * CSRCAP;
    for (int i = tid; i < tot; i += 512) cp[i] = lcsr[i];
}

// xs0[i] = bf16(dis[i] * x[i,:]) packed 2/dword; dummy rows (n) of BOTH xs
// arrays zeroed (pad slots gather row n).
__global__ void scale_x_kernel(const float* __restrict__ x, const float* __restrict__ dis,
                               unsigned* __restrict__ xs0, unsigned* __restrict__ xs1, int n) {
    int i = blockIdx.x * blockDim.x + threadIdx.x;  // over (n+1)*32 dwords
    int total = (n + 1) * (D_FEAT / 2);
    if (i >= total) return;
    int node = i >> 5;
    if (node < n) {
        float s = dis[node];
        float2 v = ((const float2*)x)[i];
        xs0[i] = pack_bf16_2(s * v.x, s * v.y);
    } else {
        xs0[i] = 0u;
        xs1[i] = 0u;  // dummy row of hop-1 output
    }
}

// Hop 1: xs1[r,:] = bf16( dis[r]^2 * ( xs0[r,:] + sum_c xs0[c,:] ) ).
// Wave owns rows 4*wave..4*wave+3; quarter q owns row 4*wave+q.
// Lane (q,ql) holds features 4ql..4ql+3 in h0..h3.
__global__ __launch_bounds__(256) void spmm_hop1_kernel(const uint2* __restrict__ xs_in,
                                                        uint2* __restrict__ xs_out,
                                                        const uint2* __restrict__ row_info,
                                                        const int* __restrict__ csr_col,
                                                        const float* __restrict__ dis, int n) {
    int wave = (blockIdx.x * blockDim.x + threadIdx.x) >> 6;
    int lane = threadIdx.x & 63;
    int q = lane >> 4, ql = lane & 15;
    int r = wave * 4 + q;
    bool valid = r < n;
    int s = 0, len = 0;
    if (valid) { uint2 info = row_info[r]; s = (int)info.x; len = (int)info.y; }
    int maxlen = len;
    maxlen = max(maxlen, __shfl_xor(maxlen, 16, 64));
    maxlen = max(maxlen, __shfl_xor(maxlen, 32, 64));

    float h0 = 0.f, h1 = 0.f, h2 = 0.f, h3 = 0.f;
    const uint4* cp = (const uint4*)(csr_col + s);  // s is a multiple of 4
    for (int base = 0; base < maxlen; base += 8) {
        uint2 u0 = make_uint2(0u, 0u), u1 = u0, u2 = u0, u3 = u0;
        uint2 u4 = u0, u5 = u0, u6 = u0, u7 = u0;
        if (base < len) {
            uint4 cv = cp[base >> 2];
            u0 = xs_in[cv.x * 16 + ql];
            u1 = xs_in[cv.y * 16 + ql];
            u2 = xs_in[cv.z * 16 + ql];
            u3 = xs_in[cv.w * 16 + ql];
        }
        if (base + 4 < len) {
            uint4 cv = cp[(base >> 2) + 1];
            u4 = xs_in[cv.x * 16 + ql];
            u5 = xs_in[cv.y * 16 + ql];
            u6 = xs_in[cv.z * 16 + ql];
            u7 = xs_in[cv.w * 16 + ql];
        }
        acc2(u0.x, h0, h1); acc2(u0.y, h2, h3);
        acc2(u1.x, h0, h1); acc2(u1.y, h2, h3);
        acc2(u2.x, h0, h1); acc2(u2.y, h2, h3);
        acc2(u3.x, h0, h1); acc2(u3.y, h2, h3);
        acc2(u4.x, h0, h1); acc2(u4.y, h2, h3);
        acc2(u5.x, h0, h1); acc2(u5.y, h2, h3);
        acc2(u6.x, h0, h1); acc2(u6.y, h2, h3);
        acc2(u7.x, h0, h1); acc2(u7.y, h2, h3);
    }
    if (valid) {
        uint2 us = xs_in[r * 16 + ql];  // self term
        acc2(us.x, h0, h1); acc2(us.y, h2, h3);
        float dr = dis[r];
        float dr2 = dr * dr;
        xs_out[r * 16 + ql] = make_uint2(pack_bf16_2(dr2 * h0, dr2 * h1),
                                         pack_bf16_2(dr2 * h2, dr2 * h3));
    }
}

// Hop 2 fused with logits + log_softmax. h2[r,:] = dis[r]*(xs1[r,:]+sum_c xs1[c,:]).
// GEMV: lane ql covers classes ql, ql+16, (ql<8) ql+32; features broadcast via
// per-lane-source __shfl within the quarter.
__global__ __launch_bounds__(256) void spmm_logits_kernel(const uint2* __restrict__ xs_in,
                                                          const uint2* __restrict__ row_info,
                                                          const int* __restrict__ csr_col,
                                                          const float* __restrict__ dis,
                                                          const float* __restrict__ W,
                                                          const float* __restrict__ b,
                                                          float* __restrict__ out, int n) {
    __shared__ float Wl[D_FEAT * NCLS];
    __shared__ float bl[NCLS];
    for (int i = threadIdx.x; i < D_FEAT * NCLS; i += blockDim.x) Wl[i] = W[i];
    for (int i = threadIdx.x; i < NCLS; i += blockDim.x) bl[i] = b[i];
    __syncthreads();

    int wave = (blockIdx.x * blockDim.x + threadIdx.x) >> 6;
    int lane = threadIdx.x & 63;
    int q = lane >> 4, ql = lane & 15;
    int r = wave * 4 + q;
    bool valid = r < n;
    int s = 0, len = 0;
    if (valid) { uint2 info = row_info[r]; s = (int)info.x; len = (int)info.y; }
    int maxlen = len;
    maxlen = max(maxlen, __shfl_xor(maxlen, 16, 64));
    maxlen = max(maxlen, __shfl_xor(maxlen, 32, 64));

    float h0 = 0.f, h1 = 0.f, h2 = 0.f, h3 = 0.f;
    const uint4* cp = (const uint4*)(csr_col + s);
    for (int base = 0; base < maxlen; base += 8) {
        uint2 u0 = make_uint2(0u, 0u), u1 = u0, u2 = u0, u3 = u0;
        uint2 u4 = u0, u5 = u0, u6 = u0, u7 = u0;
        if (base < len) {
            uint4 cv = cp[base >> 2];
            u0 = xs_in[cv.x * 16 + ql];
            u1 = xs_in[cv.y * 16 + ql];
            u2 = xs_in[cv.z * 16 + ql];
            u3 = xs_in[cv.w * 16 + ql];
        }
        if (base + 4 < len) {
            uint4 cv = cp[(base >> 2) + 1];
            u4 = xs_in[cv.x * 16 + ql];
            u5 = xs_in[cv.y * 16 + ql];
            u6 = xs_in[cv.z * 16 + ql];
            u7 = xs_in[cv.w * 16 + ql];
        }
        acc2(u0.x, h0, h1); acc2(u0.y, h2, h3);
        acc2(u1.x, h0, h1); acc2(u1.y, h2, h3);
        acc2(u2.x, h0, h1); acc2(u2.y, h2, h3);
        acc2(u3.x, h0, h1); acc2(u3.y, h2, h3);
        acc2(u4.x, h0, h1); acc2(u4.y, h2, h3);
        acc2(u5.x, h0, h1); acc2(u5.y, h2, h3);
        acc2(u6.x, h0, h1); acc2(u6.y, h2, h3);
        acc2(u7.x, h0, h1); acc2(u7.y, h2, h3);
    }

    float y0, y1, y2;
    {
        uint2 us = valid ? xs_in[r * 16 + ql] : make_uint2(0u, 0u);  // self term
        acc2(us.x, h0, h1); acc2(us.y, h2, h3);
        float dr = valid ? dis[r] : 0.f;
        h0 *= dr; h1 *= dr; h2 *= dr; h3 *= dr;

        int c0 = ql, c1 = ql + 16;
        int c2 = (ql < 8) ? (ql + 32) : ql;  // dup addr -> broadcast, no conflict
        y0 = bl[c0]; y1 = bl[c1]; y2 = bl[c2];
        int qbase = q << 4;
#pragma unroll
        for (int d = 0; d < D_FEAT; d++) {
            int src = qbase + (d >> 2);
            float xv;
            switch (d & 3) {
                case 0: xv = __shfl(h0, src, 64); break;
                case 1: xv = __shfl(h1, src, 64); break;
                case 2: xv = __shfl(h2, src, 64); break;
                default: xv = __shfl(h3, src, 64); break;
            }
            y0 += xv * Wl[d * NCLS + c0];
            y1 += xv * Wl[d * NCLS + c1];
            y2 += xv * Wl[d * NCLS + c2];
        }
    }

    bool has3 = (ql < 8);
    float m = fmaxf(y0, y1);
    if (has3) m = fmaxf(m, y2);
#pragma unroll
    for (int o = 8; o > 0; o >>= 1) m = fmaxf(m, __shfl_xor(m, o, 64));
    float sm = __expf(y0 - m) + __expf(y1 - m) + (has3 ? __expf(y2 - m) : 0.f);
#pragma unroll
    for (int o = 8; o > 0; o >>= 1) sm += __shfl_xor(sm, o, 64);
    float lse = m + __logf(sm);

    if (valid) {
        float* op = out + (long long)r * NCLS;
        op[ql] = y0 - lse;
        op[ql + 16] = y1 - lse;
        if (has3) op[ql + 32] = y2 - lse;
    }
}

extern "C" void kernel_launch(void* const* d_in, const int* in_sizes, int n_in,
                              void* d_out, int out_size, void* d_ws, size_t ws_size,
                              hipStream_t stream) {
    const float* x  = (const float*)d_in[0];
    const int*   ei = (const int*)d_in[1];   // [2, E] flat: rows then cols (int32)
    const float* W  = (const float*)d_in[2]; // [64, 40]
    const float* b  = (const float*)d_in[3]; // [40]
    float* out = (float*)d_out;

    const int n = in_sizes[0] / D_FEAT;      // 100000
    const int e = in_sizes[1] / 2;           // 1600000
    const int nb = (n + BROWS - 1) / BROWS;  // 196

    const int* rows = ei;
    const int* cols = ei + e;

    // ws layout (int units, all segments 256-int aligned):
    //   bucket_cursor[nb] | dis[n] | row_info[n] (uint2) |
    //   bins[nb*BINCAP] | csr_col[nb*CSRCAP] | xs0 | xs1       (~44 MB)
    size_t na = ((size_t)n + 256) & ~(size_t)255;
    int*      bucket_cursor = (int*)d_ws;
    float*    dis           = (float*)(bucket_cursor + 256);
    uint2*    row_info      = (uint2*)(dis + na);
    unsigned* bins          = (unsigned*)(row_info + na);
    int*      csr_col       = (int*)(bins + (size_t)nb * BINCAP);
    unsigned* xs0           = (unsigned*)(csr_col + (size_t)nb * CSRCAP);
    unsigned* xs1           = xs0 + (size_t)(n + 1) * (D_FEAT / 2);

    const int BS = 256;

    zero_cursors_kernel<<<1, 256, 0, stream>>>(bucket_cursor, nb);
    {
        int blocks = (e + BS * EPT - 1) / (BS * EPT);  // 625
        bin_edges_kernel<<<blocks, BS, 0, stream>>>(rows, cols, bucket_cursor, bins, e, nb);
    }
    build_csr_kernel<<<nb, 512, 0, stream>>>(bins, bucket_cursor, csr_col, row_info, dis, n);
    {
        int tot = (n + 1) * (D_FEAT / 2);
        scale_x_kernel<<<(tot + BS - 1) / BS, BS, 0, stream>>>(x, dis, xs0, xs1, n);
    }

    int nwaves = (n + 3) / 4;                 // 4 rows per wave
    int blocks = (nwaves * 64 + BS - 1) / BS;
    spmm_hop1_kernel<<<blocks, BS, 0, stream>>>((const uint2*)xs0, (uint2*)xs1,
                                                row_info, csr_col, dis, n);
    spmm_logits_kernel<<<blocks, BS, 0, stream>>>((const uint2*)xs1, row_info, csr_col,
                                                  dis, W, b, out, n);
}

// Round 8
// 244.134 us; speedup vs baseline: 3.7545x; 1.0363x over previous
//
#include <hip/hip_runtime.h>
#include <math.h>

// SGC: K=2 hops of D^-1/2 (A+I) D^-1/2, then x@W+b, then log_softmax.
// N=100000, D=64, C=40, E=1600000.
//
// R8: deeper gather pipeline + binning locality.
//  - SpMM: quarter-wave per row (16 lanes x uint2 = one 128B bf16 row), FOUR
//    predicated groups of 4 slots per iteration -> up to 16 row-gathers + 4
//    col-loads in flight per wave (2x R7's MLP). Same padding (4).
//  - bin_edges: EPT=25 (250 blocks) -> per-(block,bucket) runs ~33 edges
//    (>=2 full lines), 2.5x fewer global cursor atomics.
//  - build_csr: deterministic per-row insertion sort (sorted col order is a
//    pure function of the edge multiset -> bit-identical output across
//    replays); int4 copy-out.
// Hop 2 fused with 64x40 GEMV + log_softmax.

#define D_FEAT 64
#define NCLS 40
#define BROWS 512       // rows per bucket
#define BROWS_LOG 9
#define BINCAP 10240    // per-bucket edge capacity (mean 8192, sd ~90)
#define CSRCAP 12288    // per-bucket csr capacity (max padded = 10240+3*512 = 11776)
#define EPT 25          // edges per thread in bin_edges (250 blocks)

__device__ __forceinline__ unsigned pack_bf16_2(float lo, float hi) {
    unsigned ulo = __float_as_uint(lo);
    unsigned uhi = __float_as_uint(hi);
    ulo = (ulo + 0x7fffu + ((ulo >> 16) & 1u)) >> 16;           // RNE
    uhi = (uhi + 0x7fffu + ((uhi >> 16) & 1u)) & 0xffff0000u;   // RNE
    return uhi | ulo;
}

__device__ __forceinline__ void acc2(unsigned u, float& a, float& b) {
    a += __uint_as_float(u << 16);
    b += __uint_as_float(u & 0xffff0000u);
}

__global__ void zero_cursors_kernel(int* __restrict__ cur, int nb) {
    int i = blockIdx.x * blockDim.x + threadIdx.x;
    if (i < nb) cur[i] = 0;
}

// Bin edges into per-bucket regions. Packed entry: (row&511)<<17 | col.
// (Requires n <= 131072 so col fits 17 bits; n = 100000 here.)
__global__ __launch_bounds__(256) void bin_edges_kernel(const int* __restrict__ rows,
                                                        const int* __restrict__ cols,
                                                        int* __restrict__ bucket_cursor,
                                                        unsigned* __restrict__ bins,
                                                        int e, int nb) {
    __shared__ int cnt[512];
    for (int i = threadIdx.x; i < nb; i += 256) cnt[i] = 0;
    __syncthreads();
    int base = blockIdx.x * (256 * EPT) + threadIdx.x;
    int rr[EPT], cc[EPT];
#pragma unroll
    for (int k = 0; k < EPT; k++) {
        int idx = base + k * 256;
        if (idx < e) { rr[k] = rows[idx]; cc[k] = cols[idx]; }
        else { rr[k] = -1; cc[k] = 0; }
    }
#pragma unroll
    for (int k = 0; k < EPT; k++)
        if (rr[k] >= 0) atomicAdd(&cnt[rr[k] >> BROWS_LOG], 1);
    __syncthreads();
    for (int i = threadIdx.x; i < nb; i += 256) {
        int c = cnt[i];
        cnt[i] = (c > 0) ? atomicAdd(&bucket_cursor[i], c) : 0;  // global base
    }
    __syncthreads();
#pragma unroll
    for (int k = 0; k < EPT; k++) {
        if (rr[k] >= 0) {
            int b = rr[k] >> BROWS_LOG;
            int pos = atomicAdd(&cnt[b], 1);  // absolute pos within bucket
            bins[(size_t)b * BINCAP + pos] =
                ((unsigned)(rr[k] & (BROWS - 1)) << 17) | (unsigned)cc[k];
        }
    }
}

// One 512-thread block per bucket, all staged in LDS. Emits sorted,
// dummy-padded CSR (deterministic) + row_info + dis.
__global__ __launch_bounds__(512) void build_csr_kernel(const unsigned* __restrict__ bins,
                                                        const int* __restrict__ bucket_cursor,
                                                        int* __restrict__ csr_col,
                                                        uint2* __restrict__ row_info,
                                                        float* __restrict__ dis, int n) {
    __shared__ int cnt[512];
    __shared__ int sm[512];
    __shared__ int cur[512];
    __shared__ int lcsr[CSRCAP];  // 48 KB; total static LDS = 54 KB
    int b = blockIdx.x;
    int tid = threadIdx.x;
    int m = bucket_cursor[b];
    cnt[tid] = 0;
    __syncthreads();
    const unsigned* bp = bins + (size_t)b * BINCAP;
    for (int i = tid; i < m; i += 512) atomicAdd(&cnt[bp[i] >> 17], 1);
    __syncthreads();
    int c = cnt[tid];
    int padded = (c + 3) & ~3;
    int r = b * BROWS + tid;
    if (r < n) dis[r] = rsqrtf(1.0f + (float)c);
    sm[tid] = padded;
    __syncthreads();
    for (int off = 1; off < 512; off <<= 1) {
        int t = (tid >= off) ? sm[tid - off] : 0;
        __syncthreads();
        sm[tid] += t;
        __syncthreads();
    }
    int off0 = sm[tid] - padded;  // exclusive scan
    cur[tid] = off0;
    if (r < n) row_info[r] = make_uint2((unsigned)(b * CSRCAP + off0), (unsigned)padded);
    __syncthreads();
    for (int i = tid; i < m; i += 512) {
        unsigned u = bp[i];
        int pos = atomicAdd(&cur[u >> 17], 1);
        lcsr[pos] = (int)(u & 0x1FFFFu);
    }
    __syncthreads();
    // Per-row insertion sort (determinism: sorted multiset order) + dummy pad.
    for (int i2 = off0 + 1; i2 < off0 + c; i2++) {
        int key = lcsr[i2];
        int j = i2 - 1;
        while (j >= off0 && lcsr[j] > key) { lcsr[j + 1] = lcsr[j]; j--; }
        lcsr[j + 1] = key;
    }
    for (int j = off0 + c; j < off0 + padded; j++) lcsr[j] = n;
    __syncthreads();
    int tot = sm[511];  // total padded slots (multiple of 4)
    int4* cp4 = (int4*)(csr_col + (size_t)b * CSRCAP);
    const int4* l4 = (const int4*)lcsr;
    for (int i = tid; i < (tot >> 2); i += 512) cp4[i] = l4[i];
}

// xs0[i] = bf16(dis[i] * x[i,:]) packed 2/dword; dummy rows (n) of BOTH xs
// arrays zeroed (pad slots gather row n).
__global__ void scale_x_kernel(const float* __restrict__ x, const float* __restrict__ dis,
                               unsigned* __restrict__ xs0, unsigned* __restrict__ xs1, int n) {
    int i = blockIdx.x * blockDim.x + threadIdx.x;  // over (n+1)*32 dwords
    int total = (n + 1) * (D_FEAT / 2);
    if (i >= total) return;
    int node = i >> 5;
    if (node < n) {
        float s = dis[node];
        float2 v = ((const float2*)x)[i];
        xs0[i] = pack_bf16_2(s * v.x, s * v.y);
    } else {
        xs0[i] = 0u;
        xs1[i] = 0u;  // dummy row of hop-1 output
    }
}

// Gather 16 slots (4 predicated groups of 4) for one quarter's row chunk.
#define GATHER16(cp, xs_in, ql, base, len)                                  \
    uint2 u0 = make_uint2(0u, 0u), u1 = u0, u2 = u0, u3 = u0;               \
    uint2 u4 = u0, u5 = u0, u6 = u0, u7 = u0;                               \
    uint2 u8 = u0, u9 = u0, u10 = u0, u11 = u0;                             \
    uint2 u12 = u0, u13 = u0, u14 = u0, u15 = u0;                           \
    if (base < len) {                                                       \
        uint4 cv = cp[(base >> 2) + 0];                                     \
        u0 = xs_in[cv.x * 16 + ql]; u1 = xs_in[cv.y * 16 + ql];             \
        u2 = xs_in[cv.z * 16 + ql]; u3 = xs_in[cv.w * 16 + ql];             \
    }                                                                       \
    if (base + 4 < len) {                                                   \
        uint4 cv = cp[(base >> 2) + 1];                                     \
        u4 = xs_in[cv.x * 16 + ql]; u5 = xs_in[cv.y * 16 + ql];             \
        u6 = xs_in[cv.z * 16 + ql]; u7 = xs_in[cv.w * 16 + ql];             \
    }                                                                       \
    if (base + 8 < len) {                                                   \
        uint4 cv = cp[(base >> 2) + 2];                                     \
        u8 = xs_in[cv.x * 16 + ql]; u9 = xs_in[cv.y * 16 + ql];             \
        u10 = xs_in[cv.z * 16 + ql]; u11 = xs_in[cv.w * 16 + ql];           \
    }                                                                       \
    if (base + 12 < len) {                                                  \
        uint4 cv = cp[(base >> 2) + 3];                                     \
        u12 = xs_in[cv.x * 16 + ql]; u13 = xs_in[cv.y * 16 + ql];           \
        u14 = xs_in[cv.z * 16 + ql]; u15 = xs_in[cv.w * 16 + ql];           \
    }                                                                       \
    acc2(u0.x, h0, h1); acc2(u0.y, h2, h3);                                 \
    acc2(u1.x, h0, h1); acc2(u1.y, h2, h3);                                 \
    acc2(u2.x, h0, h1); acc2(u2.y, h2, h3);                                 \
    acc2(u3.x, h0, h1); acc2(u3.y, h2, h3);                                 \
    acc2(u4.x, h0, h1); acc2(u4.y, h2, h3);                                 \
    acc2(u5.x, h0, h1); acc2(u5.y, h2, h3);                                 \
    acc2(u6.x, h0, h1); acc2(u6.y, h2, h3);                                 \
    acc2(u7.x, h0, h1); acc2(u7.y, h2, h3);                                 \
    acc2(u8.x, h0, h1); acc2(u8.y, h2, h3);                                 \
    acc2(u9.x, h0, h1); acc2(u9.y, h2, h3);                                 \
    acc2(u10.x, h0, h1); acc2(u10.y, h2, h3);                               \
    acc2(u11.x, h0, h1); acc2(u11.y, h2, h3);                               \
    acc2(u12.x, h0, h1); acc2(u12.y, h2, h3);                               \
    acc2(u13.x, h0, h1); acc2(u13.y, h2, h3);                               \
    acc2(u14.x, h0, h1); acc2(u14.y, h2, h3);                               \
    acc2(u15.x, h0, h1); acc2(u15.y, h2, h3);

// Hop 1: xs1[r,:] = bf16( dis[r]^2 * ( xs0[r,:] + sum_c xs0[c,:] ) ).
// Quarter q owns row 4*wave+q; lane (q,ql) holds features 4ql..4ql+3.
__global__ __launch_bounds__(256) void spmm_hop1_kernel(const uint2* __restrict__ xs_in,
                                                        uint2* __restrict__ xs_out,
                                                        const uint2* __restrict__ row_info,
                                                        const int* __restrict__ csr_col,
                                                        const float* __restrict__ dis, int n) {
    int wave = (blockIdx.x * blockDim.x + threadIdx.x) >> 6;
    int lane = threadIdx.x & 63;
    int q = lane >> 4, ql = lane & 15;
    int r = wave * 4 + q;
    bool valid = r < n;
    int s = 0, len = 0;
    if (valid) { uint2 info = row_info[r]; s = (int)info.x; len = (int)info.y; }
    int maxlen = len;
    maxlen = max(maxlen, __shfl_xor(maxlen, 16, 64));
    maxlen = max(maxlen, __shfl_xor(maxlen, 32, 64));

    float h0 = 0.f, h1 = 0.f, h2 = 0.f, h3 = 0.f;
    const uint4* cp = (const uint4*)(csr_col + s);  // s is a multiple of 4
    for (int base = 0; base < maxlen; base += 16) {
        GATHER16(cp, xs_in, ql, base, len)
    }
    if (valid) {
        uint2 us = xs_in[r * 16 + ql];  // self term
        acc2(us.x, h0, h1); acc2(us.y, h2, h3);
        float dr = dis[r];
        float dr2 = dr * dr;
        xs_out[r * 16 + ql] = make_uint2(pack_bf16_2(dr2 * h0, dr2 * h1),
                                         pack_bf16_2(dr2 * h2, dr2 * h3));
    }
}

// Hop 2 fused with logits + log_softmax. h2[r,:] = dis[r]*(xs1[r,:]+sum_c xs1[c,:]).
// GEMV: lane ql covers classes ql, ql+16, (ql<8) ql+32; features broadcast via
// per-lane-source __shfl within the quarter.
__global__ __launch_bounds__(256) void spmm_logits_kernel(const uint2* __restrict__ xs_in,
                                                          const uint2* __restrict__ row_info,
                                                          const int* __restrict__ csr_col,
                                                          const float* __restrict__ dis,
                                                          const float* __restrict__ W,
                                                          const float* __restrict__ b,
                                                          float* __restrict__ out, int n) {
    __shared__ float Wl[D_FEAT * NCLS];
    __shared__ float bl[NCLS];
    for (int i = threadIdx.x; i < D_FEAT * NCLS; i += blockDim.x) Wl[i] = W[i];
    for (int i = threadIdx.x; i < NCLS; i += blockDim.x) bl[i] = b[i];
    __syncthreads();

    int wave = (blockIdx.x * blockDim.x + threadIdx.x) >> 6;
    int lane = threadIdx.x & 63;
    int q = lane >> 4, ql = lane & 15;
    int r = wave * 4 + q;
    bool valid = r < n;
    int s = 0, len = 0;
    if (valid) { uint2 info = row_info[r]; s = (int)info.x; len = (int)info.y; }
    int maxlen = len;
    maxlen = max(maxlen, __shfl_xor(maxlen, 16, 64));
    maxlen = max(maxlen, __shfl_xor(maxlen, 32, 64));

    float h0 = 0.f, h1 = 0.f, h2 = 0.f, h3 = 0.f;
    const uint4* cp = (const uint4*)(csr_col + s);
    for (int base = 0; base < maxlen; base += 16) {
        GATHER16(cp, xs_in, ql, base, len)
    }

    float y0, y1, y2;
    {
        uint2 us = valid ? xs_in[r * 16 + ql] : make_uint2(0u, 0u);  // self term
        acc2(us.x, h0, h1); acc2(us.y, h2, h3);
        float dr = valid ? dis[r] : 0.f;
        h0 *= dr; h1 *= dr; h2 *= dr; h3 *= dr;

        int c0 = ql, c1 = ql + 16;
        int c2 = (ql < 8) ? (ql + 32) : ql;  // dup addr -> broadcast, no conflict
        y0 = bl[c0]; y1 = bl[c1]; y2 = bl[c2];
        int qbase = q << 4;
#pragma unroll
        for (int d = 0; d < D_FEAT; d++) {
            int src = qbase + (d >> 2);
            float xv;
            switch (d & 3) {
                case 0: xv = __shfl(h0, src, 64); break;
                case 1: xv = __shfl(h1, src, 64); break;
                case 2: xv = __shfl(h2, src, 64); break;
                default: xv = __shfl(h3, src, 64); break;
            }
            y0 += xv * Wl[d * NCLS + c0];
            y1 += xv * Wl[d * NCLS + c1];
            y2 += xv * Wl[d * NCLS + c2];
        }
    }

    bool has3 = (ql < 8);
    float m = fmaxf(y0, y1);
    if (has3) m = fmaxf(m, y2);
#pragma unroll
    for (int o = 8; o > 0; o >>= 1) m = fmaxf(m, __shfl_xor(m, o, 64));
    float sm = __expf(y0 - m) + __expf(y1 - m) + (has3 ? __expf(y2 - m) : 0.f);
#pragma unroll
    for (int o = 8; o > 0; o >>= 1) sm += __shfl_xor(sm, o, 64);
    float lse = m + __logf(sm);

    if (valid) {
        float* op = out + (long long)r * NCLS;
        op[ql] = y0 - lse;
        op[ql + 16] = y1 - lse;
        if (has3) op[ql + 32] = y2 - lse;
    }
}

extern "C" void kernel_launch(void* const* d_in, const int* in_sizes, int n_in,
                              void* d_out, int out_size, void* d_ws, size_t ws_size,
                              hipStream_t stream) {
    const float* x  = (const float*)d_in[0];
    const int*   ei = (const int*)d_in[1];   // [2, E] flat: rows then cols (int32)
    const float* W  = (const float*)d_in[2]; // [64, 40]
    const float* b  = (const float*)d_in[3]; // [40]
    float* out = (float*)d_out;

    const int n = in_sizes[0] / D_FEAT;      // 100000
    const int e = in_sizes[1] / 2;           // 1600000
    const int nb = (n + BROWS - 1) / BROWS;  // 196

    const int* rows = ei;
    const int* cols = ei + e;

    // ws layout (int units, all segments 256-int aligned):
    //   bucket_cursor[nb] | dis[n] | row_info[n] (uint2) |
    //   bins[nb*BINCAP] | csr_col[nb*CSRCAP] | xs0 | xs1       (~44 MB)
    size_t na = ((size_t)n + 256) & ~(size_t)255;
    int*      bucket_cursor = (int*)d_ws;
    float*    dis           = (float*)(bucket_cursor + 256);
    uint2*    row_info      = (uint2*)(dis + na);
    unsigned* bins          = (unsigned*)(row_info + na);
    int*      csr_col       = (int*)(bins + (size_t)nb * BINCAP);
    unsigned* xs0           = (unsigned*)(csr_col + (size_t)nb * CSRCAP);
    unsigned* xs1           = xs0 + (size_t)(n + 1) * (D_FEAT / 2);

    const int BS = 256;

    zero_cursors_kernel<<<1, 256, 0, stream>>>(bucket_cursor, nb);
    {
        int blocks = (e + BS * EPT - 1) / (BS * EPT);  // 250
        bin_edges_kernel<<<blocks, BS, 0, stream>>>(rows, cols, bucket_cursor, bins, e, nb);
    }
    build_csr_kernel<<<nb, 512, 0, stream>>>(bins, bucket_cursor, csr_col, row_info, dis, n);
    {
        int tot = (n + 1) * (D_FEAT / 2);
        scale_x_kernel<<<(tot + BS - 1) / BS, BS, 0, stream>>>(x, dis, xs0, xs1, n);
    }

    int nwaves = (n + 3) / 4;                 // 4 rows per wave
    int blocks = (nwaves * 64 + BS - 1) / BS;
    spmm_hop1_kernel<<<blocks, BS, 0, stream>>>((const uint2*)xs0, (uint2*)xs1,
                                                row_info, csr_col, dis, n);
    spmm_logits_kernel<<<blocks, BS, 0, stream>>>((const uint2*)xs1, row_info, csr_col,
                                                  dis, W, b, out, n);
}